// Round 2
// baseline (448.639 us; speedup 1.0000x reference)
//
#include <hip/hip_runtime.h>
#include <cstdint>
#include <cstddef>

#define DEVINL __device__ __forceinline__

static constexpr int Bdim = 2, Ldim = 32, Cdim = 128, Hdim = 32, Wdim = 32;
static constexpr int HW  = Hdim * Wdim;         // 1024
static constexpr int CHW = Cdim * HW;           // 131072
static constexpr size_t OUT0_ELEMS = (size_t)Bdim * Ldim * CHW;  // 8388608
static constexpr size_t OUT1_CPLX  = (size_t)Bdim * CHW;         // 262144 complex elems

DEVINL float2 cmul(float2 a, float2 b) {
    return make_float2(a.x*b.x - a.y*b.y, a.x*b.y + a.y*b.x);
}
DEVINL int bitrev5(int v) {
    return ((v&1)<<4) | ((v&2)<<2) | (v&4) | ((v&8)>>2) | ((v&16)>>4);
}

// ---------------- FFT2 (32x32) in LDS, radix-2 DIT, 256 threads/block ----------------
template<int INV>
DEVINL void fft2_lds(float2 (*s)[33], const float2* tw, int t) {
#pragma unroll
    for (int st = 0; st < 5; ++st) {
        const int half = 1 << st;
#pragma unroll
        for (int q = 0; q < 2; ++q) {
            int bid = t + q*256;          // 0..511
            int row = bid & 31;
            int bf  = bid >> 5;           // 0..15
            int g = bf >> st;
            int j = bf & (half - 1);
            int i0 = (g << (st+1)) + j;
            float2 w = tw[j << (4 - st)];
            if (INV) w.y = -w.y;
            float2 a0 = s[row][i0];
            float2 a1 = s[row][i0 + half];
            float2 tm = cmul(w, a1);
            s[row][i0]        = make_float2(a0.x + tm.x, a0.y + tm.y);
            s[row][i0 + half] = make_float2(a0.x - tm.x, a0.y - tm.y);
        }
        __syncthreads();
    }
    {
        int i0 = t * 4;
        int r = i0 >> 5, w = i0 & 31;
        int rb = bitrev5(r);
        float2 v0 = s[rb][w], v1 = s[rb][w+1], v2 = s[rb][w+2], v3 = s[rb][w+3];
        __syncthreads();
        s[r][w] = v0; s[r][w+1] = v1; s[r][w+2] = v2; s[r][w+3] = v3;
        __syncthreads();
    }
#pragma unroll
    for (int st = 0; st < 5; ++st) {
        const int half = 1 << st;
#pragma unroll
        for (int q = 0; q < 2; ++q) {
            int bid = t + q*256;
            int col = bid & 31;
            int bf  = bid >> 5;
            int g = bf >> st;
            int j = bf & (half - 1);
            int i0 = (g << (st+1)) + j;
            float2 w = tw[j << (4 - st)];
            if (INV) w.y = -w.y;
            float2 a0 = s[i0][col];
            float2 a1 = s[i0 + half][col];
            float2 tm = cmul(w, a1);
            s[i0][col]        = make_float2(a0.x + tm.x, a0.y + tm.y);
            s[i0 + half][col] = make_float2(a0.x - tm.x, a0.y - tm.y);
        }
        __syncthreads();
    }
}

__global__ __launch_bounds__(256) void fft2_fwd_kernel(const float* __restrict__ x,
                                                       float2* __restrict__ Hf) {
    __shared__ float2 s[32][33];
    __shared__ float2 tw[16];
    const int t = threadIdx.x;
    const size_t slice = blockIdx.x;
    if (t < 16) {
        float a = -6.283185307179586f * (float)t / 32.0f;
        tw[t] = make_float2(cosf(a), sinf(a));
    }
    float4 v = reinterpret_cast<const float4*>(x + slice*HW)[t];
    const int i0 = t*4, r = i0 >> 5, w = i0 & 31;
    s[r][bitrev5(w)]   = make_float2(v.x, 0.f);
    s[r][bitrev5(w+1)] = make_float2(v.y, 0.f);
    s[r][bitrev5(w+2)] = make_float2(v.z, 0.f);
    s[r][bitrev5(w+3)] = make_float2(v.w, 0.f);
    __syncthreads();
    fft2_lds<0>(s, tw, t);
    float2* hp = Hf + slice*HW;
    float4* hp4 = reinterpret_cast<float4*>(hp + i0);
    hp4[0] = make_float4(s[r][w].x,   s[r][w].y,   s[r][w+1].x, s[r][w+1].y);
    hp4[1] = make_float4(s[r][w+2].x, s[r][w+2].y, s[r][w+3].x, s[r][w+3].y);
}

__global__ __launch_bounds__(256) void fft2_inv_kernel(float2* __restrict__ Hf) {
    __shared__ float2 s[32][33];
    __shared__ float2 tw[16];
    const int t = threadIdx.x;
    const size_t slice = blockIdx.x;
    if (t < 16) {
        float a = -6.283185307179586f * (float)t / 32.0f;
        tw[t] = make_float2(cosf(a), sinf(a));
    }
    float2* hp = Hf + slice*HW;
    const int i0 = t*4, r = i0 >> 5, w = i0 & 31;
    const float4* hp4 = reinterpret_cast<const float4*>(hp + i0);
    float4 u0 = hp4[0], u1 = hp4[1];
    s[r][bitrev5(w)]   = make_float2(u0.x, u0.y);
    s[r][bitrev5(w+1)] = make_float2(u0.z, u0.w);
    s[r][bitrev5(w+2)] = make_float2(u1.x, u1.y);
    s[r][bitrev5(w+3)] = make_float2(u1.z, u1.w);
    __syncthreads();
    fft2_lds<1>(s, tw, t);
    const float sc = 1.0f / 1024.0f;
    float4* wp4 = reinterpret_cast<float4*>(hp + i0);
    wp4[0] = make_float4(s[r][w].x*sc,   s[r][w].y*sc,   s[r][w+1].x*sc, s[r][w+1].y*sc);
    wp4[1] = make_float4(s[r][w+2].x*sc, s[r][w+2].y*sc, s[r][w+3].x*sc, s[r][w+3].y*sc);
}

// ---------------- channel mix ----------------
template<int MODE>
__global__ __launch_bounds__(256) void mix_kernel(
    float2* __restrict__ Hf,
    const float* __restrict__ Wre, const float* __restrict__ Wim,
    const float* __restrict__ bre, const float* __restrict__ bim,
    const float* __restrict__ pl,
    float* __restrict__ outr)
{
    __shared__ float2 As[32][134];
    __shared__ float2 Bs[32][64];
    const int bx  = blockIdx.x;      // 64 bl * 16 tiles
    const int bl  = bx >> 4;
    const int hw0 = (bx & 15) << 6;
    const int t   = threadIdx.x;
    const int wv  = t >> 6;
    const int ln  = t & 63;
    float2 acc[32];
#pragma unroll
    for (int i = 0; i < 32; ++i) acc[i] = make_float2(0.f, 0.f);
    float2* __restrict__ base = Hf + (size_t)bl * CHW;

    for (int c0 = 0; c0 < Cdim; c0 += 32) {
        __syncthreads();
#pragma unroll
        for (int q = 0; q < 16; ++q) {
            int idx = q*256 + t;
            int o = idx >> 5, cc = idx & 31;
            As[cc][o] = make_float2(Wre[o*Cdim + c0 + cc], Wim[o*Cdim + c0 + cc]);
        }
#pragma unroll
        for (int q = 0; q < 8; ++q) {
            int idx = q*256 + t;
            int cc = idx >> 6, j = idx & 63;
            Bs[cc][j] = base[(size_t)(c0+cc)*HW + hw0 + j];
        }
        __syncthreads();
#pragma unroll 4
        for (int cc = 0; cc < 32; ++cc) {
            const float2 bv = Bs[cc][ln];
            const float4* arow4 = reinterpret_cast<const float4*>(&As[cc][wv*32]);
#pragma unroll
            for (int i2 = 0; i2 < 16; ++i2) {
                float4 av = arow4[i2];
                int i = i2*2;
                acc[i].x   = fmaf(av.x,  bv.x, acc[i].x);
                acc[i].x   = fmaf(-av.y, bv.y, acc[i].x);
                if (MODE == 0) {
                    acc[i].y = fmaf(av.x, bv.y, acc[i].y);
                    acc[i].y = fmaf(av.y, bv.x, acc[i].y);
                }
                acc[i+1].x = fmaf(av.z,  bv.x, acc[i+1].x);
                acc[i+1].x = fmaf(-av.w, bv.y, acc[i+1].x);
                if (MODE == 0) {
                    acc[i+1].y = fmaf(av.z, bv.y, acc[i+1].y);
                    acc[i+1].y = fmaf(av.w, bv.x, acc[i+1].y);
                }
            }
        }
    }
    const int hw = hw0 + ln;
    const int hrow = hw >> 5;
    if (MODE == 0) {
#pragma unroll
        for (int i = 0; i < 32; ++i) {
            int o = wv*32 + i;
            float g = expf(pl[(2*Cdim + o)*Hdim + hrow]);
            float2 r;
            r.x = (acc[i].x + bre[o]) * g;
            r.y = (acc[i].y + bim[o]) * g;
            base[(size_t)o*HW + hw] = r;
        }
    } else {
#pragma unroll
        for (int i = 0; i < 32; ++i) {
            int o = wv*32 + i;
            outr[(size_t)bl*CHW + (size_t)o*HW + hw] = acc[i].x + bre[o];
        }
    }
}

// ---------------- recurrence over L (in-place) + last-hidden output ----------------
// CPLX=1: out1 is interleaved float2 (complex64 .view(float32) layout)
// CPLX=0: out1 is real part only (harness cast complex64 -> float32)
template<int CPLX>
__global__ __launch_bounds__(256) void scan_kernel(
    float2* __restrict__ Hf, const float* __restrict__ pl, float* __restrict__ out1)
{
    const int idx = blockIdx.x*256 + threadIdx.x;   // 0..262143 = B*C*H*W
    const int b   = idx >> 17;
    const int chw = idx & (CHW - 1);
    const int c   = chw >> 10;
    const int h   = (chw >> 5) & 31;
    const float nu = expf(pl[c*Hdim + h]);
    const float th = expf(pl[(Cdim + c)*Hdim + h]);
    const float rr = expf(-nu);
    const float lr = rr * cosf(th);
    const float li = rr * sinf(th);
    float2 y = make_float2(0.f, 0.f);
    const size_t basei = (size_t)b * Ldim * CHW + chw;
#pragma unroll 4
    for (int l = 0; l < Ldim; ++l) {
        float2 hv = Hf[basei + (size_t)l*CHW];
        float yr = fmaf(lr, y.x, fmaf(-li, y.y, hv.x));
        float yi = fmaf(lr, y.y, fmaf( li, y.x, hv.y));
        y = make_float2(yr, yi);
        Hf[basei + (size_t)l*CHW] = y;
    }
    const size_t o = (size_t)b*CHW + chw;
    if (CPLX) {
        reinterpret_cast<float2*>(out1)[o] = y;
    } else {
        out1[o] = y.x;
    }
}

// ---------------- LayerNorm over (C,H,W) per (b,l) ----------------
__global__ __launch_bounds__(256) void ln_reduce_kernel(const float* __restrict__ hr,
                                                        float2* __restrict__ partial) {
    const int bid = blockIdx.x;          // 64 bl * 16 parts
    const int bl = bid >> 4, part = bid & 15;
    const float* p = hr + (size_t)bl*CHW + part*8192;
    const int t = threadIdx.x;
    float s = 0.f, sq = 0.f;
    const float4* p4 = reinterpret_cast<const float4*>(p);
#pragma unroll
    for (int q = 0; q < 8; ++q) {
        float4 v = p4[q*256 + t];
        s  += v.x + v.y + v.z + v.w;
        sq += v.x*v.x + v.y*v.y + v.z*v.z + v.w*v.w;
    }
#pragma unroll
    for (int off = 32; off > 0; off >>= 1) {
        s  += __shfl_down(s, off);
        sq += __shfl_down(sq, off);
    }
    __shared__ float2 red[4];
    if ((t & 63) == 0) red[t >> 6] = make_float2(s, sq);
    __syncthreads();
    if (t == 0) {
        float2 a = red[0], b2 = red[1], c2 = red[2], d = red[3];
        partial[bid] = make_float2(a.x + b2.x + c2.x + d.x, a.y + b2.y + c2.y + d.y);
    }
}

__global__ __launch_bounds__(64) void ln_finish_kernel(const float2* __restrict__ partial,
                                                       float2* __restrict__ stats) {
    const int bl = blockIdx.x;
    const int t = threadIdx.x;
    float s = 0.f, sq = 0.f;
    if (t < 16) { float2 v = partial[bl*16 + t]; s = v.x; sq = v.y; }
#pragma unroll
    for (int off = 8; off > 0; off >>= 1) {
        s  += __shfl_down(s, off);
        sq += __shfl_down(sq, off);
    }
    if (t == 0) {
        const float invN = 1.0f / (float)CHW;
        float mean = s * invN;
        float var  = sq * invN - mean*mean;
        stats[bl] = make_float2(mean, rsqrtf(var + 1e-5f));
    }
}

__global__ __launch_bounds__(256) void ln_apply_kernel(
    float* __restrict__ out0, const float* __restrict__ x,
    const float* __restrict__ lnw, const float* __restrict__ lnb,
    const float2* __restrict__ stats)
{
    const int idx4 = blockIdx.x*256 + threadIdx.x;   // 0..2097151 (x4 floats)
    const int i = idx4 * 4;
    const int bl = i >> 17;
    const int chw4 = (i & (CHW - 1)) >> 2;
    const float2 st = stats[bl];
    float4 h  = reinterpret_cast<float4*>(out0)[idx4];
    float4 xv = reinterpret_cast<const float4*>(x)[idx4];
    float4 w  = reinterpret_cast<const float4*>(lnw)[chw4];
    float4 bb = reinterpret_cast<const float4*>(lnb)[chw4];
    const float m = st.x, rs = st.y;
    float4 r;
    r.x = fmaf((h.x - m)*rs, w.x, bb.x) + xv.x;
    r.y = fmaf((h.y - m)*rs, w.y, bb.y) + xv.y;
    r.z = fmaf((h.z - m)*rs, w.z, bb.z) + xv.z;
    r.w = fmaf((h.w - m)*rs, w.w, bb.w) + xv.w;
    reinterpret_cast<float4*>(out0)[idx4] = r;
}

// ---------------- launch ----------------
extern "C" void kernel_launch(void* const* d_in, const int* in_sizes, int n_in,
                              void* d_out, int out_size, void* d_ws, size_t ws_size,
                              hipStream_t stream)
{
    const float* x     = (const float*)d_in[0];
    const float* pl    = (const float*)d_in[1];
    const float* Wb_re = (const float*)d_in[2];
    const float* Wb_im = (const float*)d_in[3];
    const float* bb_re = (const float*)d_in[4];
    const float* bb_im = (const float*)d_in[5];
    const float* Wc_re = (const float*)d_in[6];
    const float* Wc_im = (const float*)d_in[7];
    const float* bc_re = (const float*)d_in[8];
    const float* bc_im = (const float*)d_in[9];
    const float* ln_w  = (const float*)d_in[10];
    const float* ln_b  = (const float*)d_in[11];

    float* out0 = (float*)d_out;
    float* out1 = out0 + OUT0_ELEMS;

    char* ws = (char*)d_ws;
    float2* Hf      = (float2*)ws;                                   // 67,108,864 B
    float2* partial = (float2*)(ws + OUT0_ELEMS*sizeof(float2));
    float2* stats   = partial + 1024;

    const int NS = Bdim*Ldim*Cdim;      // 8192 fft slices

    // Does the harness view the complex64 output as interleaved float32 pairs
    // (out_size = OUT0 + 2*OUT1) or cast it to float32 real part
    // (out_size = OUT0 + OUT1)?  Branch on out_size (constant across calls).
    const bool interleaved = ((size_t)out_size >= OUT0_ELEMS + 2*OUT1_CPLX);

    fft2_fwd_kernel<<<NS, 256, 0, stream>>>(x, Hf);
    mix_kernel<0><<<1024, 256, 0, stream>>>(Hf, Wb_re, Wb_im, bb_re, bb_im, pl, nullptr);
    if (interleaved)
        scan_kernel<1><<<1024, 256, 0, stream>>>(Hf, pl, out1);
    else
        scan_kernel<0><<<1024, 256, 0, stream>>>(Hf, pl, out1);
    fft2_inv_kernel<<<NS, 256, 0, stream>>>(Hf);
    mix_kernel<1><<<1024, 256, 0, stream>>>(Hf, Wc_re, Wc_im, bc_re, bc_im, pl, out0);
    ln_reduce_kernel<<<1024, 256, 0, stream>>>(out0, partial);
    ln_finish_kernel<<<64, 64, 0, stream>>>(partial, stats);
    ln_apply_kernel<<<8192, 256, 0, stream>>>(out0, x, ln_w, ln_b, stats);
}

// Round 3
// 193.067 us; speedup vs baseline: 2.3237x; 2.3237x over previous
//
#include <hip/hip_runtime.h>
#include <cstdint>
#include <cstddef>

#define DEVINL __device__ __forceinline__

static constexpr int Bdim = 2, Ldim = 32, Cdim = 128, Hdim = 32, Wdim = 32;
static constexpr int HW  = Hdim * Wdim;         // 1024
static constexpr int CHW = Cdim * HW;           // 131072
static constexpr size_t OUT0_ELEMS = (size_t)Bdim * Ldim * CHW;  // 8388608
static constexpr size_t OUT1_CPLX  = (size_t)Bdim * CHW;         // 262144 complex elems

typedef __attribute__((ext_vector_type(8))) short short8v;   // 8 bf16 (4 VGPR)
typedef __attribute__((ext_vector_type(4))) float f32x4;     // MFMA C/D

DEVINL float2 cmul(float2 a, float2 b) {
    return make_float2(a.x*b.x - a.y*b.y, a.x*b.y + a.y*b.x);
}
DEVINL int bitrev5(int v) {
    return ((v&1)<<4) | ((v&2)<<2) | (v&4) | ((v&8)>>2) | ((v&16)>>4);
}
DEVINL unsigned short f2bf(float v) {               // RNE f32 -> bf16 bits
    unsigned u = __float_as_uint(v);
    return (unsigned short)((u + 0x7FFFu + ((u >> 16) & 1u)) >> 16);
}
DEVINL void bfsplit(float v, short& hi, short& lo) {
    unsigned short hb = f2bf(v);
    hi = (short)hb;
    float hf = __uint_as_float(((unsigned)hb) << 16);
    lo = (short)f2bf(v - hf);
}

// ======================= FFT2 (32x32), unchanged (verified) =======================
template<int INV>
DEVINL void fft2_lds(float2 (*s)[33], const float2* tw, int t) {
#pragma unroll
    for (int st = 0; st < 5; ++st) {
        const int half = 1 << st;
#pragma unroll
        for (int q = 0; q < 2; ++q) {
            int bid = t + q*256;
            int row = bid & 31;
            int bf  = bid >> 5;
            int g = bf >> st;
            int j = bf & (half - 1);
            int i0 = (g << (st+1)) + j;
            float2 w = tw[j << (4 - st)];
            if (INV) w.y = -w.y;
            float2 a0 = s[row][i0];
            float2 a1 = s[row][i0 + half];
            float2 tm = cmul(w, a1);
            s[row][i0]        = make_float2(a0.x + tm.x, a0.y + tm.y);
            s[row][i0 + half] = make_float2(a0.x - tm.x, a0.y - tm.y);
        }
        __syncthreads();
    }
    {
        int i0 = t * 4;
        int r = i0 >> 5, w = i0 & 31;
        int rb = bitrev5(r);
        float2 v0 = s[rb][w], v1 = s[rb][w+1], v2 = s[rb][w+2], v3 = s[rb][w+3];
        __syncthreads();
        s[r][w] = v0; s[r][w+1] = v1; s[r][w+2] = v2; s[r][w+3] = v3;
        __syncthreads();
    }
#pragma unroll
    for (int st = 0; st < 5; ++st) {
        const int half = 1 << st;
#pragma unroll
        for (int q = 0; q < 2; ++q) {
            int bid = t + q*256;
            int col = bid & 31;
            int bf  = bid >> 5;
            int g = bf >> st;
            int j = bf & (half - 1);
            int i0 = (g << (st+1)) + j;
            float2 w = tw[j << (4 - st)];
            if (INV) w.y = -w.y;
            float2 a0 = s[i0][col];
            float2 a1 = s[i0 + half][col];
            float2 tm = cmul(w, a1);
            s[i0][col]        = make_float2(a0.x + tm.x, a0.y + tm.y);
            s[i0 + half][col] = make_float2(a0.x - tm.x, a0.y - tm.y);
        }
        __syncthreads();
    }
}

__global__ __launch_bounds__(256) void fft2_fwd_kernel(const float* __restrict__ x,
                                                       float2* __restrict__ Hf) {
    __shared__ float2 s[32][33];
    __shared__ float2 tw[16];
    const int t = threadIdx.x;
    const size_t slice = blockIdx.x;
    if (t < 16) {
        float a = -6.283185307179586f * (float)t / 32.0f;
        tw[t] = make_float2(cosf(a), sinf(a));
    }
    float4 v = reinterpret_cast<const float4*>(x + slice*HW)[t];
    const int i0 = t*4, r = i0 >> 5, w = i0 & 31;
    s[r][bitrev5(w)]   = make_float2(v.x, 0.f);
    s[r][bitrev5(w+1)] = make_float2(v.y, 0.f);
    s[r][bitrev5(w+2)] = make_float2(v.z, 0.f);
    s[r][bitrev5(w+3)] = make_float2(v.w, 0.f);
    __syncthreads();
    fft2_lds<0>(s, tw, t);
    float2* hp = Hf + slice*HW;
    float4* hp4 = reinterpret_cast<float4*>(hp + i0);
    hp4[0] = make_float4(s[r][w].x,   s[r][w].y,   s[r][w+1].x, s[r][w+1].y);
    hp4[1] = make_float4(s[r][w+2].x, s[r][w+2].y, s[r][w+3].x, s[r][w+3].y);
}

__global__ __launch_bounds__(256) void fft2_inv_kernel(float2* __restrict__ Hf) {
    __shared__ float2 s[32][33];
    __shared__ float2 tw[16];
    const int t = threadIdx.x;
    const size_t slice = blockIdx.x;
    if (t < 16) {
        float a = -6.283185307179586f * (float)t / 32.0f;
        tw[t] = make_float2(cosf(a), sinf(a));
    }
    float2* hp = Hf + slice*HW;
    const int i0 = t*4, r = i0 >> 5, w = i0 & 31;
    const float4* hp4 = reinterpret_cast<const float4*>(hp + i0);
    float4 u0 = hp4[0], u1 = hp4[1];
    s[r][bitrev5(w)]   = make_float2(u0.x, u0.y);
    s[r][bitrev5(w+1)] = make_float2(u0.z, u0.w);
    s[r][bitrev5(w+2)] = make_float2(u1.x, u1.y);
    s[r][bitrev5(w+3)] = make_float2(u1.z, u1.w);
    __syncthreads();
    fft2_lds<1>(s, tw, t);
    const float sc = 1.0f / 1024.0f;
    float4* wp4 = reinterpret_cast<float4*>(hp + i0);
    wp4[0] = make_float4(s[r][w].x*sc,   s[r][w].y*sc,   s[r][w+1].x*sc, s[r][w+1].y*sc);
    wp4[1] = make_float4(s[r][w+2].x*sc, s[r][w+2].y*sc, s[r][w+3].x*sc, s[r][w+3].y*sc);
}

// ======================= A-pack: weights -> MFMA fragment order, bf16 hi/lo ==========
// Logical matrices (M=128 x K=256):
//   a=0: A0re = [Wb_re | -Wb_im]   a=1: A0im = [Wb_im | Wb_re]   a=2: A1re = [Wc_re | -Wc_im]
// Fragment f = m*8 + kc (m=0..7 M-tiles of 16, kc=0..7 K-chunks of 32).
// Element (lane, j): A[m*16 + (lane&15)][kc*32 + (lane>>4)*8 + j].
// Arrays (each 128*256 shorts = 64KB): [A0re_hi, A0re_lo, A0im_hi, A0im_lo, A1re_hi, A1re_lo]
__global__ __launch_bounds__(256) void pack_w_kernel(
    const float* __restrict__ Wb_re, const float* __restrict__ Wb_im,
    const float* __restrict__ Wc_re, const float* __restrict__ Wc_im,
    short* __restrict__ Apack)
{
    const int gid = blockIdx.x*256 + threadIdx.x;    // 0..12287
    const int a    = gid >> 12;
    const int rem  = gid & 4095;
    const int f    = rem >> 6;
    const int lane = rem & 63;
    const int m  = f >> 3, kc = f & 7;
    const int row = m*16 + (lane & 15);
    const int kbase = kc*32 + ((lane >> 4) << 3);
    short8v hi8, lo8;
#pragma unroll
    for (int j = 0; j < 8; ++j) {
        const int k = kbase + j;
        const int half = k >> 7;
        const int c = k & 127;
        float v;
        if (a == 0)      v = half ? -Wb_im[row*Cdim + c] : Wb_re[row*Cdim + c];
        else if (a == 1) v = half ?  Wb_re[row*Cdim + c] : Wb_im[row*Cdim + c];
        else             v = half ? -Wc_im[row*Cdim + c] : Wc_re[row*Cdim + c];
        short h, l; bfsplit(v, h, l);
        hi8[j] = h; lo8[j] = l;
    }
    const size_t off = (size_t)(f*64 + lane)*8;
    *reinterpret_cast<short8v*>(Apack + (size_t)(2*a)  *32768 + off) = hi8;
    *reinterpret_cast<short8v*>(Apack + (size_t)(2*a+1)*32768 + off) = lo8;
}

// ======================= MFMA channel mix ==========================================
// Per block: one (b,l) slice x 64 hw columns.  out[o,n] = sum_k A[o,k]*B[k,n],
// K=256 (k<128: re(h[c]), k>=128: im(h[c])).  Split-bf16 3-pass per term.
// LDS: B fragments [hi/lo][kc=8][nt=4][lane=64][j=8] bf16 = 64 KB.
// Waves: wave w computes o in [w*32, w*32+32) (m-frags 2w, 2w+1), all 4 n-tiles.
template<int MODE>
__global__ __launch_bounds__(256) void mix_mfma_kernel(
    float2* __restrict__ Hf,
    const short* __restrict__ Apack,
    const float* __restrict__ bre, const float* __restrict__ bim,
    const float* __restrict__ pl,
    float* __restrict__ outr)
{
    __shared__ short Bhl[2][8][4][64][8];
    const int bx  = blockIdx.x;          // 64 bl * 16 tiles
    const int bl  = bx >> 4;
    const int hw0 = (bx & 15) << 6;
    const int t   = threadIdx.x;
    const int wv  = t >> 6;
    const int lane = t & 63;
    float2* __restrict__ base = Hf + (size_t)bl * CHW;

    // ---- stage B tile: 128 channels x 64 cols, f32 complex -> bf16 hi/lo fragments ----
#pragma unroll
    for (int i = 0; i < 4; ++i) {
        const int idx = i*256 + t;           // (kc4, nt, ln): kc4=idx>>8, nt=(idx>>6)&3, ln=idx&63
        const int kc4 = idx >> 8;
        const int nt  = (idx >> 6) & 3;
        const int ln  = idx & 63;
        const int c0  = kc4*32 + ((ln >> 4) << 3);
        const int n   = nt*16 + (ln & 15);
        const float2* src = base + (size_t)c0*HW + hw0 + n;
        short8v hre, lre, him, lim;
#pragma unroll
        for (int j = 0; j < 8; ++j) {
            float2 hv = src[(size_t)j*HW];
            short h, l;
            bfsplit(hv.x, h, l); hre[j] = h; lre[j] = l;
            bfsplit(hv.y, h, l); him[j] = h; lim[j] = l;
        }
        *reinterpret_cast<short8v*>(&Bhl[0][kc4][nt][ln][0])   = hre;
        *reinterpret_cast<short8v*>(&Bhl[0][kc4+4][nt][ln][0]) = him;
        *reinterpret_cast<short8v*>(&Bhl[1][kc4][nt][ln][0])   = lre;
        *reinterpret_cast<short8v*>(&Bhl[1][kc4+4][nt][ln][0]) = lim;
    }
    __syncthreads();

    // ---- K-loop: 8 chunks of 32 ----
    f32x4 accRe[2][4];
    f32x4 accIm[2][4];
#pragma unroll
    for (int mi = 0; mi < 2; ++mi)
#pragma unroll
        for (int nt = 0; nt < 4; ++nt) {
            accRe[mi][nt] = (f32x4)(0.0f);
            accIm[mi][nt] = (f32x4)(0.0f);
        }

    const short* Are_hi = Apack + (MODE == 0 ? 0 : 4)*32768;
    const short* Are_lo = Are_hi + 32768;
    const short* Aim_hi = Apack + 2*32768;   // only used in MODE 0
    const short* Aim_lo = Aim_hi + 32768;

#pragma unroll 2
    for (int kc = 0; kc < 8; ++kc) {
        short8v bh[4], blo[4];
#pragma unroll
        for (int nt = 0; nt < 4; ++nt) {
            bh[nt]  = *reinterpret_cast<const short8v*>(&Bhl[0][kc][nt][lane][0]);
            blo[nt] = *reinterpret_cast<const short8v*>(&Bhl[1][kc][nt][lane][0]);
        }
#pragma unroll
        for (int mi = 0; mi < 2; ++mi) {
            const int m = wv*2 + mi;
            const size_t off = (size_t)((m*8 + kc)*64 + lane)*8;
            const short8v arh = *reinterpret_cast<const short8v*>(Are_hi + off);
            const short8v arl = *reinterpret_cast<const short8v*>(Are_lo + off);
#pragma unroll
            for (int nt = 0; nt < 4; ++nt) {
                accRe[mi][nt] = __builtin_amdgcn_mfma_f32_16x16x32_bf16(arh, bh[nt],  accRe[mi][nt], 0, 0, 0);
                accRe[mi][nt] = __builtin_amdgcn_mfma_f32_16x16x32_bf16(arh, blo[nt], accRe[mi][nt], 0, 0, 0);
                accRe[mi][nt] = __builtin_amdgcn_mfma_f32_16x16x32_bf16(arl, bh[nt],  accRe[mi][nt], 0, 0, 0);
            }
            if (MODE == 0) {
                const short8v aih = *reinterpret_cast<const short8v*>(Aim_hi + off);
                const short8v ail = *reinterpret_cast<const short8v*>(Aim_lo + off);
#pragma unroll
                for (int nt = 0; nt < 4; ++nt) {
                    accIm[mi][nt] = __builtin_amdgcn_mfma_f32_16x16x32_bf16(aih, bh[nt],  accIm[mi][nt], 0, 0, 0);
                    accIm[mi][nt] = __builtin_amdgcn_mfma_f32_16x16x32_bf16(aih, blo[nt], accIm[mi][nt], 0, 0, 0);
                    accIm[mi][nt] = __builtin_amdgcn_mfma_f32_16x16x32_bf16(ail, bh[nt],  accIm[mi][nt], 0, 0, 0);
                }
            }
        }
    }

    // ---- epilogue.  D layout: col = lane&15, row = (lane>>4)*4 + r ----
    const int col   = lane & 15;
    const int rbase = (lane >> 4) * 4;
    const int h0    = hw0 >> 5;
#pragma unroll
    for (int mi = 0; mi < 2; ++mi) {
#pragma unroll
        for (int r = 0; r < 4; ++r) {
            const int o = wv*32 + mi*16 + rbase + r;
            if (MODE == 0) {
                const float br = bre[o], bi = bim[o];
                const float g0 = expf(pl[(2*Cdim + o)*Hdim + h0]);
                const float g1 = expf(pl[(2*Cdim + o)*Hdim + h0 + 1]);
#pragma unroll
                for (int nt = 0; nt < 4; ++nt) {
                    const float g = (nt < 2) ? g0 : g1;
                    const int hw = hw0 + nt*16 + col;
                    float2 rv;
                    rv.x = (accRe[mi][nt][r] + br) * g;
                    rv.y = (accIm[mi][nt][r] + bi) * g;
                    base[(size_t)o*HW + hw] = rv;
                }
            } else {
                const float br = bre[o];
#pragma unroll
                for (int nt = 0; nt < 4; ++nt) {
                    const int hw = hw0 + nt*16 + col;
                    outr[(size_t)bl*CHW + (size_t)o*HW + hw] = accRe[mi][nt][r] + br;
                }
            }
        }
    }
}

// ======================= scan over L (unchanged, verified) =======================
template<int CPLX>
__global__ __launch_bounds__(256) void scan_kernel(
    float2* __restrict__ Hf, const float* __restrict__ pl, float* __restrict__ out1)
{
    const int idx = blockIdx.x*256 + threadIdx.x;   // 0..262143 = B*C*H*W
    const int b   = idx >> 17;
    const int chw = idx & (CHW - 1);
    const int c   = chw >> 10;
    const int h   = (chw >> 5) & 31;
    const float nu = expf(pl[c*Hdim + h]);
    const float th = expf(pl[(Cdim + c)*Hdim + h]);
    const float rr = expf(-nu);
    const float lr = rr * cosf(th);
    const float li = rr * sinf(th);
    float2 y = make_float2(0.f, 0.f);
    const size_t basei = (size_t)b * Ldim * CHW + chw;
#pragma unroll 4
    for (int l = 0; l < Ldim; ++l) {
        float2 hv = Hf[basei + (size_t)l*CHW];
        float yr = fmaf(lr, y.x, fmaf(-li, y.y, hv.x));
        float yi = fmaf(lr, y.y, fmaf( li, y.x, hv.y));
        y = make_float2(yr, yi);
        Hf[basei + (size_t)l*CHW] = y;
    }
    const size_t o = (size_t)b*CHW + chw;
    if (CPLX) {
        reinterpret_cast<float2*>(out1)[o] = y;
    } else {
        out1[o] = y.x;
    }
}

// ======================= LayerNorm (unchanged, verified) =======================
__global__ __launch_bounds__(256) void ln_reduce_kernel(const float* __restrict__ hr,
                                                        float2* __restrict__ partial) {
    const int bid = blockIdx.x;          // 64 bl * 16 parts
    const int bl = bid >> 4, part = bid & 15;
    const float* p = hr + (size_t)bl*CHW + part*8192;
    const int t = threadIdx.x;
    float s = 0.f, sq = 0.f;
    const float4* p4 = reinterpret_cast<const float4*>(p);
#pragma unroll
    for (int q = 0; q < 8; ++q) {
        float4 v = p4[q*256 + t];
        s  += v.x + v.y + v.z + v.w;
        sq += v.x*v.x + v.y*v.y + v.z*v.z + v.w*v.w;
    }
#pragma unroll
    for (int off = 32; off > 0; off >>= 1) {
        s  += __shfl_down(s, off);
        sq += __shfl_down(sq, off);
    }
    __shared__ float2 red[4];
    if ((t & 63) == 0) red[t >> 6] = make_float2(s, sq);
    __syncthreads();
    if (t == 0) {
        float2 a = red[0], b2 = red[1], c2 = red[2], d = red[3];
        partial[bid] = make_float2(a.x + b2.x + c2.x + d.x, a.y + b2.y + c2.y + d.y);
    }
}

__global__ __launch_bounds__(64) void ln_finish_kernel(const float2* __restrict__ partial,
                                                       float2* __restrict__ stats) {
    const int bl = blockIdx.x;
    const int t = threadIdx.x;
    float s = 0.f, sq = 0.f;
    if (t < 16) { float2 v = partial[bl*16 + t]; s = v.x; sq = v.y; }
#pragma unroll
    for (int off = 8; off > 0; off >>= 1) {
        s  += __shfl_down(s, off);
        sq += __shfl_down(sq, off);
    }
    if (t == 0) {
        const float invN = 1.0f / (float)CHW;
        float mean = s * invN;
        float var  = sq * invN - mean*mean;
        stats[bl] = make_float2(mean, rsqrtf(var + 1e-5f));
    }
}

__global__ __launch_bounds__(256) void ln_apply_kernel(
    float* __restrict__ out0, const float* __restrict__ x,
    const float* __restrict__ lnw, const float* __restrict__ lnb,
    const float2* __restrict__ stats)
{
    const int idx4 = blockIdx.x*256 + threadIdx.x;
    const int i = idx4 * 4;
    const int bl = i >> 17;
    const int chw4 = (i & (CHW - 1)) >> 2;
    const float2 st = stats[bl];
    float4 h  = reinterpret_cast<float4*>(out0)[idx4];
    float4 xv = reinterpret_cast<const float4*>(x)[idx4];
    float4 w  = reinterpret_cast<const float4*>(lnw)[chw4];
    float4 bb = reinterpret_cast<const float4*>(lnb)[chw4];
    const float m = st.x, rs = st.y;
    float4 r;
    r.x = fmaf((h.x - m)*rs, w.x, bb.x) + xv.x;
    r.y = fmaf((h.y - m)*rs, w.y, bb.y) + xv.y;
    r.z = fmaf((h.z - m)*rs, w.z, bb.z) + xv.z;
    r.w = fmaf((h.w - m)*rs, w.w, bb.w) + xv.w;
    reinterpret_cast<float4*>(out0)[idx4] = r;
}

// ======================= launch =======================
extern "C" void kernel_launch(void* const* d_in, const int* in_sizes, int n_in,
                              void* d_out, int out_size, void* d_ws, size_t ws_size,
                              hipStream_t stream)
{
    const float* x     = (const float*)d_in[0];
    const float* pl    = (const float*)d_in[1];
    const float* Wb_re = (const float*)d_in[2];
    const float* Wb_im = (const float*)d_in[3];
    const float* bb_re = (const float*)d_in[4];
    const float* bb_im = (const float*)d_in[5];
    const float* Wc_re = (const float*)d_in[6];
    const float* Wc_im = (const float*)d_in[7];
    const float* bc_re = (const float*)d_in[8];
    const float* bc_im = (const float*)d_in[9];
    const float* ln_w  = (const float*)d_in[10];
    const float* ln_b  = (const float*)d_in[11];

    float* out0 = (float*)d_out;
    float* out1 = out0 + OUT0_ELEMS;

    char* ws = (char*)d_ws;
    float2* Hf      = (float2*)ws;                                   // 67,108,864 B
    float2* partial = (float2*)(ws + OUT0_ELEMS*sizeof(float2));     // 8 KB
    float2* stats   = partial + 1024;                                // 512 B
    short*  Apack   = (short*)(ws + OUT0_ELEMS*sizeof(float2) + 16384);  // 384 KB

    const int NS = Bdim*Ldim*Cdim;      // 8192 fft slices
    const bool interleaved = ((size_t)out_size >= OUT0_ELEMS + 2*OUT1_CPLX);

    pack_w_kernel<<<48, 256, 0, stream>>>(Wb_re, Wb_im, Wc_re, Wc_im, Apack);
    fft2_fwd_kernel<<<NS, 256, 0, stream>>>(x, Hf);
    mix_mfma_kernel<0><<<1024, 256, 0, stream>>>(Hf, Apack, bb_re, bb_im, pl, nullptr);
    if (interleaved)
        scan_kernel<1><<<1024, 256, 0, stream>>>(Hf, pl, out1);
    else
        scan_kernel<0><<<1024, 256, 0, stream>>>(Hf, pl, out1);
    fft2_inv_kernel<<<NS, 256, 0, stream>>>(Hf);
    mix_mfma_kernel<1><<<1024, 256, 0, stream>>>(Hf, Apack, bc_re, bc_im, pl, out0);
    ln_reduce_kernel<<<1024, 256, 0, stream>>>(out0, partial);
    ln_finish_kernel<<<64, 64, 0, stream>>>(partial, stats);
    ln_apply_kernel<<<8192, 256, 0, stream>>>(out0, x, ln_w, ln_b, stats);
}

// Round 4
// 182.791 us; speedup vs baseline: 2.4544x; 1.0562x over previous
//
#include <hip/hip_runtime.h>
#include <cstdint>
#include <cstddef>

#define DEVINL __device__ __forceinline__

static constexpr int Bdim = 2, Ldim = 32, Cdim = 128, Hdim = 32, Wdim = 32;
static constexpr int HW  = Hdim * Wdim;         // 1024
static constexpr int CHW = Cdim * HW;           // 131072
static constexpr size_t OUT0_ELEMS = (size_t)Bdim * Ldim * CHW;  // 8388608
static constexpr size_t OUT1_CPLX  = (size_t)Bdim * CHW;         // 262144 complex elems

typedef __attribute__((ext_vector_type(8))) short short8v;   // 8 bf16 (4 VGPR)
typedef __attribute__((ext_vector_type(4))) float f32x4;     // MFMA C/D

DEVINL float2 cmul(float2 a, float2 b) {
    return make_float2(a.x*b.x - a.y*b.y, a.x*b.y + a.y*b.x);
}
DEVINL int bitrev5(int v) {
    return ((v&1)<<4) | ((v&2)<<2) | (v&4) | ((v&8)>>2) | ((v&16)>>4);
}
DEVINL unsigned short f2bf(float v) {               // RNE f32 -> bf16 bits
    unsigned u = __float_as_uint(v);
    return (unsigned short)((u + 0x7FFFu + ((u >> 16) & 1u)) >> 16);
}
DEVINL void bfsplit(float v, short& hi, short& lo) {
    unsigned short hb = f2bf(v);
    hi = (short)hb;
    float hf = __uint_as_float(((unsigned)hb) << 16);
    lo = (short)f2bf(v - hf);
}

// ======================= FFT2 (32x32), unchanged (verified) =======================
template<int INV>
DEVINL void fft2_lds(float2 (*s)[33], const float2* tw, int t) {
#pragma unroll
    for (int st = 0; st < 5; ++st) {
        const int half = 1 << st;
#pragma unroll
        for (int q = 0; q < 2; ++q) {
            int bid = t + q*256;
            int row = bid & 31;
            int bf  = bid >> 5;
            int g = bf >> st;
            int j = bf & (half - 1);
            int i0 = (g << (st+1)) + j;
            float2 w = tw[j << (4 - st)];
            if (INV) w.y = -w.y;
            float2 a0 = s[row][i0];
            float2 a1 = s[row][i0 + half];
            float2 tm = cmul(w, a1);
            s[row][i0]        = make_float2(a0.x + tm.x, a0.y + tm.y);
            s[row][i0 + half] = make_float2(a0.x - tm.x, a0.y - tm.y);
        }
        __syncthreads();
    }
    {
        int i0 = t * 4;
        int r = i0 >> 5, w = i0 & 31;
        int rb = bitrev5(r);
        float2 v0 = s[rb][w], v1 = s[rb][w+1], v2 = s[rb][w+2], v3 = s[rb][w+3];
        __syncthreads();
        s[r][w] = v0; s[r][w+1] = v1; s[r][w+2] = v2; s[r][w+3] = v3;
        __syncthreads();
    }
#pragma unroll
    for (int st = 0; st < 5; ++st) {
        const int half = 1 << st;
#pragma unroll
        for (int q = 0; q < 2; ++q) {
            int bid = t + q*256;
            int col = bid & 31;
            int bf  = bid >> 5;
            int g = bf >> st;
            int j = bf & (half - 1);
            int i0 = (g << (st+1)) + j;
            float2 w = tw[j << (4 - st)];
            if (INV) w.y = -w.y;
            float2 a0 = s[i0][col];
            float2 a1 = s[i0 + half][col];
            float2 tm = cmul(w, a1);
            s[i0][col]        = make_float2(a0.x + tm.x, a0.y + tm.y);
            s[i0 + half][col] = make_float2(a0.x - tm.x, a0.y - tm.y);
        }
        __syncthreads();
    }
}

__global__ __launch_bounds__(256) void fft2_fwd_kernel(const float* __restrict__ x,
                                                       float2* __restrict__ Hf) {
    __shared__ float2 s[32][33];
    __shared__ float2 tw[16];
    const int t = threadIdx.x;
    const size_t slice = blockIdx.x;
    if (t < 16) {
        float a = -6.283185307179586f * (float)t / 32.0f;
        tw[t] = make_float2(cosf(a), sinf(a));
    }
    float4 v = reinterpret_cast<const float4*>(x + slice*HW)[t];
    const int i0 = t*4, r = i0 >> 5, w = i0 & 31;
    s[r][bitrev5(w)]   = make_float2(v.x, 0.f);
    s[r][bitrev5(w+1)] = make_float2(v.y, 0.f);
    s[r][bitrev5(w+2)] = make_float2(v.z, 0.f);
    s[r][bitrev5(w+3)] = make_float2(v.w, 0.f);
    __syncthreads();
    fft2_lds<0>(s, tw, t);
    float2* hp = Hf + slice*HW;
    float4* hp4 = reinterpret_cast<float4*>(hp + i0);
    hp4[0] = make_float4(s[r][w].x,   s[r][w].y,   s[r][w+1].x, s[r][w+1].y);
    hp4[1] = make_float4(s[r][w+2].x, s[r][w+2].y, s[r][w+3].x, s[r][w+3].y);
}

__global__ __launch_bounds__(256) void fft2_inv_kernel(float2* __restrict__ Hf) {
    __shared__ float2 s[32][33];
    __shared__ float2 tw[16];
    const int t = threadIdx.x;
    const size_t slice = blockIdx.x;
    if (t < 16) {
        float a = -6.283185307179586f * (float)t / 32.0f;
        tw[t] = make_float2(cosf(a), sinf(a));
    }
    float2* hp = Hf + slice*HW;
    const int i0 = t*4, r = i0 >> 5, w = i0 & 31;
    const float4* hp4 = reinterpret_cast<const float4*>(hp + i0);
    float4 u0 = hp4[0], u1 = hp4[1];
    s[r][bitrev5(w)]   = make_float2(u0.x, u0.y);
    s[r][bitrev5(w+1)] = make_float2(u0.z, u0.w);
    s[r][bitrev5(w+2)] = make_float2(u1.x, u1.y);
    s[r][bitrev5(w+3)] = make_float2(u1.z, u1.w);
    __syncthreads();
    fft2_lds<1>(s, tw, t);
    const float sc = 1.0f / 1024.0f;
    float4* wp4 = reinterpret_cast<float4*>(hp + i0);
    wp4[0] = make_float4(s[r][w].x*sc,   s[r][w].y*sc,   s[r][w+1].x*sc, s[r][w+1].y*sc);
    wp4[1] = make_float4(s[r][w+2].x*sc, s[r][w+2].y*sc, s[r][w+3].x*sc, s[r][w+3].y*sc);
}

// ======================= A-pack (unchanged, verified) ==========
__global__ __launch_bounds__(256) void pack_w_kernel(
    const float* __restrict__ Wb_re, const float* __restrict__ Wb_im,
    const float* __restrict__ Wc_re, const float* __restrict__ Wc_im,
    short* __restrict__ Apack)
{
    const int gid = blockIdx.x*256 + threadIdx.x;    // 0..12287
    const int a    = gid >> 12;
    const int rem  = gid & 4095;
    const int f    = rem >> 6;
    const int lane = rem & 63;
    const int m  = f >> 3, kc = f & 7;
    const int row = m*16 + (lane & 15);
    const int kbase = kc*32 + ((lane >> 4) << 3);
    short8v hi8, lo8;
#pragma unroll
    for (int j = 0; j < 8; ++j) {
        const int k = kbase + j;
        const int half = k >> 7;
        const int c = k & 127;
        float v;
        if (a == 0)      v = half ? -Wb_im[row*Cdim + c] : Wb_re[row*Cdim + c];
        else if (a == 1) v = half ?  Wb_re[row*Cdim + c] : Wb_im[row*Cdim + c];
        else             v = half ? -Wc_im[row*Cdim + c] : Wc_re[row*Cdim + c];
        short h, l; bfsplit(v, h, l);
        hi8[j] = h; lo8[j] = l;
    }
    const size_t off = (size_t)(f*64 + lane)*8;
    *reinterpret_cast<short8v*>(Apack + (size_t)(2*a)  *32768 + off) = hi8;
    *reinterpret_cast<short8v*>(Apack + (size_t)(2*a+1)*32768 + off) = lo8;
}

// ======================= MFMA channel mix (N=32 tile, 32KB LDS, 4 blocks/CU) ========
// Per block: one (b,l) slice x 32 hw columns (exactly one h-row).
// MODE 1 additionally emits per-block LN partial sums (s, sq) -> lnpart[blockIdx].
template<int MODE>
__global__ __launch_bounds__(256) void mix_mfma_kernel(
    float2* __restrict__ Hf,
    const short* __restrict__ Apack,
    const float* __restrict__ bre, const float* __restrict__ bim,
    const float* __restrict__ pl,
    float* __restrict__ outr,
    float2* __restrict__ lnpart)
{
    __shared__ short Bhl[2][8][2][64][8];   // 32 KB
    const int bx  = blockIdx.x;          // 64 bl * 32 tiles
    const int bl  = bx >> 5;
    const int hw0 = (bx & 31) << 5;
    const int t   = threadIdx.x;
    const int wv  = t >> 6;
    const int lane = t & 63;
    float2* __restrict__ base = Hf + (size_t)bl * CHW;

    // ---- stage B tile: 128 channels x 32 cols, f32 complex -> bf16 hi/lo fragments ----
#pragma unroll
    for (int i = 0; i < 2; ++i) {
        const int idx = i*256 + t;           // 512 slots: kc4(2b) nt(1b) ln(6b)
        const int kc4 = (idx >> 7) & 3;
        const int nt  = (idx >> 6) & 1;
        const int ln  = idx & 63;
        const int c0  = kc4*32 + ((ln >> 4) << 3);
        const int n   = nt*16 + (ln & 15);
        const float2* src = base + (size_t)c0*HW + hw0 + n;
        short8v hre, lre, him, lim;
#pragma unroll
        for (int j = 0; j < 8; ++j) {
            float2 hv = src[(size_t)j*HW];
            short h, l;
            bfsplit(hv.x, h, l); hre[j] = h; lre[j] = l;
            bfsplit(hv.y, h, l); him[j] = h; lim[j] = l;
        }
        *reinterpret_cast<short8v*>(&Bhl[0][kc4][nt][ln][0])   = hre;
        *reinterpret_cast<short8v*>(&Bhl[0][kc4+4][nt][ln][0]) = him;
        *reinterpret_cast<short8v*>(&Bhl[1][kc4][nt][ln][0])   = lre;
        *reinterpret_cast<short8v*>(&Bhl[1][kc4+4][nt][ln][0]) = lim;
    }
    __syncthreads();

    // ---- K-loop: 8 chunks of 32 ----
    f32x4 accRe[2][2];
    f32x4 accIm[2][2];
#pragma unroll
    for (int mi = 0; mi < 2; ++mi)
#pragma unroll
        for (int nt = 0; nt < 2; ++nt) {
            accRe[mi][nt] = (f32x4)(0.0f);
            accIm[mi][nt] = (f32x4)(0.0f);
        }

    const short* Are_hi = Apack + (MODE == 0 ? 0 : 4)*32768;
    const short* Are_lo = Are_hi + 32768;
    const short* Aim_hi = Apack + 2*32768;   // only used in MODE 0
    const short* Aim_lo = Aim_hi + 32768;

#pragma unroll 2
    for (int kc = 0; kc < 8; ++kc) {
        short8v bh[2], blo[2];
#pragma unroll
        for (int nt = 0; nt < 2; ++nt) {
            bh[nt]  = *reinterpret_cast<const short8v*>(&Bhl[0][kc][nt][lane][0]);
            blo[nt] = *reinterpret_cast<const short8v*>(&Bhl[1][kc][nt][lane][0]);
        }
#pragma unroll
        for (int mi = 0; mi < 2; ++mi) {
            const int m = wv*2 + mi;
            const size_t off = (size_t)((m*8 + kc)*64 + lane)*8;
            const short8v arh = *reinterpret_cast<const short8v*>(Are_hi + off);
            const short8v arl = *reinterpret_cast<const short8v*>(Are_lo + off);
#pragma unroll
            for (int nt = 0; nt < 2; ++nt) {
                accRe[mi][nt] = __builtin_amdgcn_mfma_f32_16x16x32_bf16(arh, bh[nt],  accRe[mi][nt], 0, 0, 0);
                accRe[mi][nt] = __builtin_amdgcn_mfma_f32_16x16x32_bf16(arh, blo[nt], accRe[mi][nt], 0, 0, 0);
                accRe[mi][nt] = __builtin_amdgcn_mfma_f32_16x16x32_bf16(arl, bh[nt],  accRe[mi][nt], 0, 0, 0);
            }
            if (MODE == 0) {
                const short8v aih = *reinterpret_cast<const short8v*>(Aim_hi + off);
                const short8v ail = *reinterpret_cast<const short8v*>(Aim_lo + off);
#pragma unroll
                for (int nt = 0; nt < 2; ++nt) {
                    accIm[mi][nt] = __builtin_amdgcn_mfma_f32_16x16x32_bf16(aih, bh[nt],  accIm[mi][nt], 0, 0, 0);
                    accIm[mi][nt] = __builtin_amdgcn_mfma_f32_16x16x32_bf16(aih, blo[nt], accIm[mi][nt], 0, 0, 0);
                    accIm[mi][nt] = __builtin_amdgcn_mfma_f32_16x16x32_bf16(ail, bh[nt],  accIm[mi][nt], 0, 0, 0);
                }
            }
        }
    }

    // ---- epilogue.  D layout: col = lane&15, row = (lane>>4)*4 + r ----
    const int col   = lane & 15;
    const int rbase = (lane >> 4) * 4;
    const int h0    = hw0 >> 5;          // single h-row per tile
    float lns = 0.f, lnq = 0.f;
#pragma unroll
    for (int mi = 0; mi < 2; ++mi) {
#pragma unroll
        for (int r = 0; r < 4; ++r) {
            const int o = wv*32 + mi*16 + rbase + r;
            if (MODE == 0) {
                const float br = bre[o], bi = bim[o];
                const float g = expf(pl[(2*Cdim + o)*Hdim + h0]);
#pragma unroll
                for (int nt = 0; nt < 2; ++nt) {
                    const int hw = hw0 + nt*16 + col;
                    float2 rv;
                    rv.x = (accRe[mi][nt][r] + br) * g;
                    rv.y = (accIm[mi][nt][r] + bi) * g;
                    base[(size_t)o*HW + hw] = rv;
                }
            } else {
                const float br = bre[o];
#pragma unroll
                for (int nt = 0; nt < 2; ++nt) {
                    const int hw = hw0 + nt*16 + col;
                    const float v = accRe[mi][nt][r] + br;
                    outr[(size_t)bl*CHW + (size_t)o*HW + hw] = v;
                    lns += v; lnq += v*v;
                }
            }
        }
    }
    if (MODE == 1) {
        // deterministic per-block LN partial: wave shuffle-reduce, then LDS cross-wave
#pragma unroll
        for (int off = 32; off > 0; off >>= 1) {
            lns += __shfl_down(lns, off);
            lnq += __shfl_down(lnq, off);
        }
        __shared__ float2 red[4];
        if (lane == 0) red[wv] = make_float2(lns, lnq);
        __syncthreads();
        if (t == 0) {
            float2 a = red[0], b2 = red[1], c2 = red[2], d = red[3];
            lnpart[bx] = make_float2(a.x + b2.x + c2.x + d.x, a.y + b2.y + c2.y + d.y);
        }
    }
}

// ======================= scan over L (unchanged, verified) =======================
template<int CPLX>
__global__ __launch_bounds__(256) void scan_kernel(
    float2* __restrict__ Hf, const float* __restrict__ pl, float* __restrict__ out1)
{
    const int idx = blockIdx.x*256 + threadIdx.x;   // 0..262143 = B*C*H*W
    const int b   = idx >> 17;
    const int chw = idx & (CHW - 1);
    const int c   = chw >> 10;
    const int h   = (chw >> 5) & 31;
    const float nu = expf(pl[c*Hdim + h]);
    const float th = expf(pl[(Cdim + c)*Hdim + h]);
    const float rr = expf(-nu);
    const float lr = rr * cosf(th);
    const float li = rr * sinf(th);
    float2 y = make_float2(0.f, 0.f);
    const size_t basei = (size_t)b * Ldim * CHW + chw;
#pragma unroll 4
    for (int l = 0; l < Ldim; ++l) {
        float2 hv = Hf[basei + (size_t)l*CHW];
        float yr = fmaf(lr, y.x, fmaf(-li, y.y, hv.x));
        float yi = fmaf(lr, y.y, fmaf( li, y.x, hv.y));
        y = make_float2(yr, yi);
        Hf[basei + (size_t)l*CHW] = y;
    }
    const size_t o = (size_t)b*CHW + chw;
    if (CPLX) {
        reinterpret_cast<float2*>(out1)[o] = y;
    } else {
        out1[o] = y.x;
    }
}

// ======================= LayerNorm finish + apply =======================
// lnpart has 32 partials per (b,l); reduce them -> stats[bl] = (mean, rstd)
__global__ __launch_bounds__(64) void ln_finish_kernel(const float2* __restrict__ lnpart,
                                                       float2* __restrict__ stats) {
    const int bl = blockIdx.x;
    const int t = threadIdx.x;
    float s = 0.f, sq = 0.f;
    if (t < 32) { float2 v = lnpart[bl*32 + t]; s = v.x; sq = v.y; }
#pragma unroll
    for (int off = 16; off > 0; off >>= 1) {
        s  += __shfl_down(s, off);
        sq += __shfl_down(sq, off);
    }
    if (t == 0) {
        const float invN = 1.0f / (float)CHW;
        float mean = s * invN;
        float var  = sq * invN - mean*mean;
        stats[bl] = make_float2(mean, rsqrtf(var + 1e-5f));
    }
}

__global__ __launch_bounds__(256) void ln_apply_kernel(
    float* __restrict__ out0, const float* __restrict__ x,
    const float* __restrict__ lnw, const float* __restrict__ lnb,
    const float2* __restrict__ stats)
{
    const int idx4 = blockIdx.x*256 + threadIdx.x;
    const int i = idx4 * 4;
    const int bl = i >> 17;
    const int chw4 = (i & (CHW - 1)) >> 2;
    const float2 st = stats[bl];
    float4 h  = reinterpret_cast<float4*>(out0)[idx4];
    float4 xv = reinterpret_cast<const float4*>(x)[idx4];
    float4 w  = reinterpret_cast<const float4*>(lnw)[chw4];
    float4 bb = reinterpret_cast<const float4*>(lnb)[chw4];
    const float m = st.x, rs = st.y;
    float4 r;
    r.x = fmaf((h.x - m)*rs, w.x, bb.x) + xv.x;
    r.y = fmaf((h.y - m)*rs, w.y, bb.y) + xv.y;
    r.z = fmaf((h.z - m)*rs, w.z, bb.z) + xv.z;
    r.w = fmaf((h.w - m)*rs, w.w, bb.w) + xv.w;
    reinterpret_cast<float4*>(out0)[idx4] = r;
}

// ======================= launch =======================
extern "C" void kernel_launch(void* const* d_in, const int* in_sizes, int n_in,
                              void* d_out, int out_size, void* d_ws, size_t ws_size,
                              hipStream_t stream)
{
    const float* x     = (const float*)d_in[0];
    const float* pl    = (const float*)d_in[1];
    const float* Wb_re = (const float*)d_in[2];
    const float* Wb_im = (const float*)d_in[3];
    const float* bb_re = (const float*)d_in[4];
    const float* bb_im = (const float*)d_in[5];
    const float* Wc_re = (const float*)d_in[6];
    const float* Wc_im = (const float*)d_in[7];
    const float* bc_re = (const float*)d_in[8];
    const float* bc_im = (const float*)d_in[9];
    const float* ln_w  = (const float*)d_in[10];
    const float* ln_b  = (const float*)d_in[11];

    float* out0 = (float*)d_out;
    float* out1 = out0 + OUT0_ELEMS;

    char* ws = (char*)d_ws;
    float2* Hf      = (float2*)ws;                                   // 67,108,864 B
    float2* lnpart  = (float2*)(ws + OUT0_ELEMS*sizeof(float2));     // 2048 float2 = 16 KB
    float2* stats   = lnpart + 2048;                                 // 512 B
    short*  Apack   = (short*)(ws + OUT0_ELEMS*sizeof(float2) + 32768);  // 384 KB

    const int NS = Bdim*Ldim*Cdim;      // 8192 fft slices
    const bool interleaved = ((size_t)out_size >= OUT0_ELEMS + 2*OUT1_CPLX);

    pack_w_kernel<<<48, 256, 0, stream>>>(Wb_re, Wb_im, Wc_re, Wc_im, Apack);
    fft2_fwd_kernel<<<NS, 256, 0, stream>>>(x, Hf);
    mix_mfma_kernel<0><<<2048, 256, 0, stream>>>(Hf, Apack, bb_re, bb_im, pl, nullptr, nullptr);
    if (interleaved)
        scan_kernel<1><<<1024, 256, 0, stream>>>(Hf, pl, out1);
    else
        scan_kernel<0><<<1024, 256, 0, stream>>>(Hf, pl, out1);
    fft2_inv_kernel<<<NS, 256, 0, stream>>>(Hf);
    mix_mfma_kernel<1><<<2048, 256, 0, stream>>>(Hf, Apack, bc_re, bc_im, pl, out0, lnpart);
    ln_finish_kernel<<<64, 64, 0, stream>>>(lnpart, stats);
    ln_apply_kernel<<<8192, 256, 0, stream>>>(out0, x, ln_w, ln_b, stats);
}

// Round 6
// 150.581 us; speedup vs baseline: 2.9794x; 1.2139x over previous
//
#include <hip/hip_runtime.h>
#include <cstdint>
#include <cstddef>

#define DEVINL __device__ __forceinline__

static constexpr int Bdim = 2, Ldim = 32, Cdim = 128, Hdim = 32, Wdim = 32;
static constexpr int HW  = Hdim * Wdim;         // 1024
static constexpr int CHW = Cdim * HW;           // 131072
static constexpr size_t OUT0_ELEMS = (size_t)Bdim * Ldim * CHW;  // 8388608
static constexpr size_t OUT1_CPLX  = (size_t)Bdim * CHW;         // 262144 complex elems

typedef __attribute__((ext_vector_type(8))) short short8v;   // 8 bf16 (4 VGPR)
typedef __attribute__((ext_vector_type(4))) float f32x4;     // MFMA C/D

DEVINL int bitrev5(int v) {
    return ((v&1)<<4) | ((v&2)<<2) | (v&4) | ((v&8)>>2) | ((v&16)>>4);
}
DEVINL unsigned short f2bf(float v) {               // RNE f32 -> bf16 bits
    unsigned u = __float_as_uint(v);
    return (unsigned short)((u + 0x7FFFu + ((u >> 16) & 1u)) >> 16);
}
DEVINL void bfsplit(float v, short& hi, short& lo) {
    unsigned short hb = f2bf(v);
    hi = (short)hb;
    float hf = __uint_as_float(((unsigned)hb) << 16);
    lo = (short)f2bf(v - hf);
}

// ================= 32-point radix-2 DIT FFT, fully in registers =================
// Input must be loaded in bit-reversed order.  Twiddles W_32^j, compile-time.
template<int INV>
DEVINL void fft32_reg(float2 v[32]) {
    constexpr float TC[16] = { 1.0f, 0.980785280f, 0.923879533f, 0.831469612f,
                               0.707106781f, 0.555570233f, 0.382683432f, 0.195090322f,
                               0.0f, -0.195090322f, -0.382683432f, -0.555570233f,
                              -0.707106781f, -0.831469612f, -0.923879533f, -0.980785280f };
    constexpr float TS[16] = { 0.0f, -0.195090322f, -0.382683432f, -0.555570233f,
                              -0.707106781f, -0.831469612f, -0.923879533f, -0.980785280f,
                              -1.0f, -0.980785280f, -0.923879533f, -0.831469612f,
                              -0.707106781f, -0.555570233f, -0.382683432f, -0.195090322f };
#pragma unroll
    for (int st = 0; st < 5; ++st) {
        const int half = 1 << st;
#pragma unroll
        for (int bf = 0; bf < 16; ++bf) {
            const int g = bf >> st;
            const int j = bf & (half - 1);
            const int i0 = (g << (st+1)) + j;
            const float wr = TC[j << (4-st)];
            const float wi = INV ? -TS[j << (4-st)] : TS[j << (4-st)];
            float2 a0 = v[i0], a1 = v[i0+half];
            float tr = wr*a1.x - wi*a1.y;
            float ti = wr*a1.y + wi*a1.x;
            v[i0]      = make_float2(a0.x+tr, a0.y+ti);
            v[i0+half] = make_float2(a0.x-tr, a0.y-ti);
        }
    }
}

// ---- forward FFT along H (real input), one thread per (b,l,c,w) column ----
__global__ __launch_bounds__(256) void fft_h_fwd_kernel(const float* __restrict__ x,
                                                        float2* __restrict__ Hf) {
    const int gid = blockIdx.x*256 + threadIdx.x;     // 0..262143
    const int w = gid & 31;
    const size_t slice = (size_t)(gid >> 5);          // (b,l,c)
    const float* src = x + slice*HW + w;
    float2 v[32];
#pragma unroll
    for (int i = 0; i < 32; ++i)
        v[i] = make_float2(src[(size_t)bitrev5(i)*Wdim], 0.f);
    fft32_reg<0>(v);
    float2* dst = Hf + slice*HW + w;
#pragma unroll
    for (int h = 0; h < 32; ++h) dst[(size_t)h*Wdim] = v[h];
}

// ---- inverse FFT along H (in-place on Hf), scale 1/32 ----
__global__ __launch_bounds__(256) void fft_h_inv_kernel(float2* __restrict__ Hf) {
    const int gid = blockIdx.x*256 + threadIdx.x;
    const int w = gid & 31;
    const size_t slice = (size_t)(gid >> 5);
    float2* p = Hf + slice*HW + w;
    float2 v[32];
#pragma unroll
    for (int i = 0; i < 32; ++i) v[i] = p[(size_t)bitrev5(i)*Wdim];
    fft32_reg<1>(v);
    const float sc = 1.0f / 32.0f;
#pragma unroll
    for (int h = 0; h < 32; ++h)
        p[(size_t)h*Wdim] = make_float2(v[h].x*sc, v[h].y*sc);
}

// ---- forward FFT along W for out1 (l=31 state), one thread per (b,c,h) row ----
template<int CPLX>
__global__ __launch_bounds__(256) void fft_w_out1_kernel(const float2* __restrict__ st31,
                                                         float* __restrict__ out1) {
    const int row = blockIdx.x*256 + threadIdx.x;   // 0..8191 = (b,c,h)
    const float2* src = st31 + (size_t)row*32;
    float2 v[32];
#pragma unroll
    for (int i = 0; i < 32; ++i) v[i] = src[bitrev5(i)];
    fft32_reg<0>(v);
    if (CPLX) {
        float2* dst = reinterpret_cast<float2*>(out1) + (size_t)row*32;
#pragma unroll
        for (int i = 0; i < 32; ++i) dst[i] = v[i];
    } else {
        float* dst = out1 + (size_t)row*32;
#pragma unroll
        for (int i = 0; i < 32; ++i) dst[i] = v[i].x;
    }
}

// ======================= A-pack (unchanged, verified) ==========
__global__ __launch_bounds__(256) void pack_w_kernel(
    const float* __restrict__ Wb_re, const float* __restrict__ Wb_im,
    const float* __restrict__ Wc_re, const float* __restrict__ Wc_im,
    short* __restrict__ Apack)
{
    const int gid = blockIdx.x*256 + threadIdx.x;    // 0..12287
    const int a    = gid >> 12;
    const int rem  = gid & 4095;
    const int f    = rem >> 6;
    const int lane = rem & 63;
    const int m  = f >> 3, kc = f & 7;
    const int row = m*16 + (lane & 15);
    const int kbase = kc*32 + ((lane >> 4) << 3);
    short8v hi8, lo8;
#pragma unroll
    for (int j = 0; j < 8; ++j) {
        const int k = kbase + j;
        const int half = k >> 7;
        const int c = k & 127;
        float v;
        if (a == 0)      v = half ? -Wb_im[row*Cdim + c] : Wb_re[row*Cdim + c];
        else if (a == 1) v = half ?  Wb_re[row*Cdim + c] : Wb_im[row*Cdim + c];
        else             v = half ? -Wc_im[row*Cdim + c] : Wc_re[row*Cdim + c];
        short h, l; bfsplit(v, h, l);
        hi8[j] = h; lo8[j] = l;
    }
    const size_t off = (size_t)(f*64 + lane)*8;
    *reinterpret_cast<short8v*>(Apack + (size_t)(2*a)  *32768 + off) = hi8;
    *reinterpret_cast<short8v*>(Apack + (size_t)(2*a+1)*32768 + off) = lo8;
}

// ======================= MFMA channel mix ========
// MODE 0 operates in the (h-freq, w-spatial) partial domain: the reference's
// per-frequency-bin bias bb corresponds to bb * delta_{w==0} here.
template<int MODE>
__global__ __launch_bounds__(256) void mix_mfma_kernel(
    float2* __restrict__ Hf,
    const short* __restrict__ Apack,
    const float* __restrict__ bre, const float* __restrict__ bim,
    const float* __restrict__ pl,
    float* __restrict__ outr,
    float2* __restrict__ lnpart)
{
    __shared__ short Bhl[2][8][2][64][8];   // 32 KB
    const int bx  = blockIdx.x;          // 64 bl * 32 tiles
    const int bl  = bx >> 5;
    const int hw0 = (bx & 31) << 5;
    const int t   = threadIdx.x;
    const int wv  = t >> 6;
    const int lane = t & 63;
    float2* __restrict__ base = Hf + (size_t)bl * CHW;

#pragma unroll
    for (int i = 0; i < 2; ++i) {
        const int idx = i*256 + t;
        const int kc4 = (idx >> 7) & 3;
        const int nt  = (idx >> 6) & 1;
        const int ln  = idx & 63;
        const int c0  = kc4*32 + ((ln >> 4) << 3);
        const int n   = nt*16 + (ln & 15);
        const float2* src = base + (size_t)c0*HW + hw0 + n;
        short8v hre, lre, him, lim;
#pragma unroll
        for (int j = 0; j < 8; ++j) {
            float2 hv = src[(size_t)j*HW];
            short h, l;
            bfsplit(hv.x, h, l); hre[j] = h; lre[j] = l;
            bfsplit(hv.y, h, l); him[j] = h; lim[j] = l;
        }
        *reinterpret_cast<short8v*>(&Bhl[0][kc4][nt][ln][0])   = hre;
        *reinterpret_cast<short8v*>(&Bhl[0][kc4+4][nt][ln][0]) = him;
        *reinterpret_cast<short8v*>(&Bhl[1][kc4][nt][ln][0])   = lre;
        *reinterpret_cast<short8v*>(&Bhl[1][kc4+4][nt][ln][0]) = lim;
    }
    __syncthreads();

    f32x4 accRe[2][2];
    f32x4 accIm[2][2];
#pragma unroll
    for (int mi = 0; mi < 2; ++mi)
#pragma unroll
        for (int nt = 0; nt < 2; ++nt) {
            accRe[mi][nt] = (f32x4)(0.0f);
            accIm[mi][nt] = (f32x4)(0.0f);
        }

    const short* Are_hi = Apack + (MODE == 0 ? 0 : 4)*32768;
    const short* Are_lo = Are_hi + 32768;
    const short* Aim_hi = Apack + 2*32768;
    const short* Aim_lo = Aim_hi + 32768;

#pragma unroll 2
    for (int kc = 0; kc < 8; ++kc) {
        short8v bh[2], blo[2];
#pragma unroll
        for (int nt = 0; nt < 2; ++nt) {
            bh[nt]  = *reinterpret_cast<const short8v*>(&Bhl[0][kc][nt][lane][0]);
            blo[nt] = *reinterpret_cast<const short8v*>(&Bhl[1][kc][nt][lane][0]);
        }
#pragma unroll
        for (int mi = 0; mi < 2; ++mi) {
            const int m = wv*2 + mi;
            const size_t off = (size_t)((m*8 + kc)*64 + lane)*8;
            const short8v arh = *reinterpret_cast<const short8v*>(Are_hi + off);
            const short8v arl = *reinterpret_cast<const short8v*>(Are_lo + off);
#pragma unroll
            for (int nt = 0; nt < 2; ++nt) {
                accRe[mi][nt] = __builtin_amdgcn_mfma_f32_16x16x32_bf16(arh, bh[nt],  accRe[mi][nt], 0, 0, 0);
                accRe[mi][nt] = __builtin_amdgcn_mfma_f32_16x16x32_bf16(arh, blo[nt], accRe[mi][nt], 0, 0, 0);
                accRe[mi][nt] = __builtin_amdgcn_mfma_f32_16x16x32_bf16(arl, bh[nt],  accRe[mi][nt], 0, 0, 0);
            }
            if (MODE == 0) {
                const short8v aih = *reinterpret_cast<const short8v*>(Aim_hi + off);
                const short8v ail = *reinterpret_cast<const short8v*>(Aim_lo + off);
#pragma unroll
                for (int nt = 0; nt < 2; ++nt) {
                    accIm[mi][nt] = __builtin_amdgcn_mfma_f32_16x16x32_bf16(aih, bh[nt],  accIm[mi][nt], 0, 0, 0);
                    accIm[mi][nt] = __builtin_amdgcn_mfma_f32_16x16x32_bf16(aih, blo[nt], accIm[mi][nt], 0, 0, 0);
                    accIm[mi][nt] = __builtin_amdgcn_mfma_f32_16x16x32_bf16(ail, bh[nt],  accIm[mi][nt], 0, 0, 0);
                }
            }
        }
    }

    const int col   = lane & 15;
    const int rbase = (lane >> 4) * 4;
    const int h0    = hw0 >> 5;          // single h-row per tile
    float lns = 0.f, lnq = 0.f;
#pragma unroll
    for (int mi = 0; mi < 2; ++mi) {
#pragma unroll
        for (int r = 0; r < 4; ++r) {
            const int o = wv*32 + mi*16 + rbase + r;
            if (MODE == 0) {
                const float br = bre[o], bi = bim[o];
                const float g = expf(pl[(2*Cdim + o)*Hdim + h0]);
#pragma unroll
                for (int nt = 0; nt < 2; ++nt) {
                    const int wcol = nt*16 + col;     // w-spatial index within row
                    // bias bb corresponds to bb * delta_{w==0} in this domain
                    const float bsel = (wcol == 0) ? 1.0f : 0.0f;
                    const int hw = hw0 + wcol;
                    float2 rv;
                    rv.x = (accRe[mi][nt][r] + br*bsel) * g;
                    rv.y = (accIm[mi][nt][r] + bi*bsel) * g;
                    base[(size_t)o*HW + hw] = rv;
                }
            } else {
                const float br = bre[o];
#pragma unroll
                for (int nt = 0; nt < 2; ++nt) {
                    const int hw = hw0 + nt*16 + col;
                    const float v = accRe[mi][nt][r] + br;
                    outr[(size_t)bl*CHW + (size_t)o*HW + hw] = v;
                    lns += v; lnq += v*v;
                }
            }
        }
    }
    if (MODE == 1) {
#pragma unroll
        for (int off = 32; off > 0; off >>= 1) {
            lns += __shfl_down(lns, off);
            lnq += __shfl_down(lnq, off);
        }
        __shared__ float2 red[4];
        if (lane == 0) red[wv] = make_float2(lns, lnq);
        __syncthreads();
        if (t == 0) {
            float2 a = red[0], b2 = red[1], c2 = red[2], d = red[3];
            lnpart[bx] = make_float2(a.x + b2.x + c2.x + d.x, a.y + b2.y + c2.y + d.y);
        }
    }
}

// ======================= scan over L (writes l=31 state to st31) =======================
__global__ __launch_bounds__(256) void scan_kernel(
    float2* __restrict__ Hf, const float* __restrict__ pl, float2* __restrict__ st31)
{
    const int idx = blockIdx.x*256 + threadIdx.x;   // 0..262143 = B*C*H*W
    const int b   = idx >> 17;
    const int chw = idx & (CHW - 1);
    const int c   = chw >> 10;
    const int h   = (chw >> 5) & 31;
    const float nu = expf(pl[c*Hdim + h]);
    const float th = expf(pl[(Cdim + c)*Hdim + h]);
    const float rr = expf(-nu);
    const float lr = rr * cosf(th);
    const float li = rr * sinf(th);
    float2 y = make_float2(0.f, 0.f);
    const size_t basei = (size_t)b * Ldim * CHW + chw;
#pragma unroll 4
    for (int l = 0; l < Ldim; ++l) {
        float2 hv = Hf[basei + (size_t)l*CHW];
        float yr = fmaf(lr, y.x, fmaf(-li, y.y, hv.x));
        float yi = fmaf(lr, y.y, fmaf( li, y.x, hv.y));
        y = make_float2(yr, yi);
        Hf[basei + (size_t)l*CHW] = y;
    }
    st31[(size_t)b*CHW + chw] = y;
}

// ======================= LayerNorm finish + apply =======================
__global__ __launch_bounds__(64) void ln_finish_kernel(const float2* __restrict__ lnpart,
                                                       float2* __restrict__ stats) {
    const int bl = blockIdx.x;
    const int t = threadIdx.x;
    float s = 0.f, sq = 0.f;
    if (t < 32) { float2 v = lnpart[bl*32 + t]; s = v.x; sq = v.y; }
#pragma unroll
    for (int off = 16; off > 0; off >>= 1) {
        s  += __shfl_down(s, off);
        sq += __shfl_down(sq, off);
    }
    if (t == 0) {
        const float invN = 1.0f / (float)CHW;
        float mean = s * invN;
        float var  = sq * invN - mean*mean;
        stats[bl] = make_float2(mean, rsqrtf(var + 1e-5f));
    }
}

__global__ __launch_bounds__(256) void ln_apply_kernel(
    float* __restrict__ out0, const float* __restrict__ x,
    const float* __restrict__ lnw, const float* __restrict__ lnb,
    const float2* __restrict__ stats)
{
    const int idx4 = blockIdx.x*256 + threadIdx.x;
    const int i = idx4 * 4;
    const int bl = i >> 17;
    const int chw4 = (i & (CHW - 1)) >> 2;
    const float2 st = stats[bl];
    float4 h  = reinterpret_cast<float4*>(out0)[idx4];
    float4 xv = reinterpret_cast<const float4*>(x)[idx4];
    float4 w  = reinterpret_cast<const float4*>(lnw)[chw4];
    float4 bb = reinterpret_cast<const float4*>(lnb)[chw4];
    const float m = st.x, rs = st.y;
    float4 r;
    r.x = fmaf((h.x - m)*rs, w.x, bb.x) + xv.x;
    r.y = fmaf((h.y - m)*rs, w.y, bb.y) + xv.y;
    r.z = fmaf((h.z - m)*rs, w.z, bb.z) + xv.z;
    r.w = fmaf((h.w - m)*rs, w.w, bb.w) + xv.w;
    reinterpret_cast<float4*>(out0)[idx4] = r;
}

// ======================= launch =======================
extern "C" void kernel_launch(void* const* d_in, const int* in_sizes, int n_in,
                              void* d_out, int out_size, void* d_ws, size_t ws_size,
                              hipStream_t stream)
{
    const float* x     = (const float*)d_in[0];
    const float* pl    = (const float*)d_in[1];
    const float* Wb_re = (const float*)d_in[2];
    const float* Wb_im = (const float*)d_in[3];
    const float* bb_re = (const float*)d_in[4];
    const float* bb_im = (const float*)d_in[5];
    const float* Wc_re = (const float*)d_in[6];
    const float* Wc_im = (const float*)d_in[7];
    const float* bc_re = (const float*)d_in[8];
    const float* bc_im = (const float*)d_in[9];
    const float* ln_w  = (const float*)d_in[10];
    const float* ln_b  = (const float*)d_in[11];

    float* out0 = (float*)d_out;
    float* out1 = out0 + OUT0_ELEMS;

    char* ws = (char*)d_ws;
    float2* Hf      = (float2*)ws;                                   // 67,108,864 B
    float2* lnpart  = (float2*)(ws + OUT0_ELEMS*sizeof(float2));     // 16 KB
    float2* stats   = lnpart + 2048;                                 // 512 B
    short*  Apack   = (short*)(ws + OUT0_ELEMS*sizeof(float2) + 32768);  // 384 KB
    float2* st31    = (float2*)(ws + OUT0_ELEMS*sizeof(float2) + 32768 + 393216); // 2 MB

    const bool interleaved = ((size_t)out_size >= OUT0_ELEMS + 2*OUT1_CPLX);

    pack_w_kernel<<<48, 256, 0, stream>>>(Wb_re, Wb_im, Wc_re, Wc_im, Apack);
    fft_h_fwd_kernel<<<1024, 256, 0, stream>>>(x, Hf);
    mix_mfma_kernel<0><<<2048, 256, 0, stream>>>(Hf, Apack, bb_re, bb_im, pl, nullptr, nullptr);
    scan_kernel<<<1024, 256, 0, stream>>>(Hf, pl, st31);
    if (interleaved)
        fft_w_out1_kernel<1><<<32, 256, 0, stream>>>(st31, out1);
    else
        fft_w_out1_kernel<0><<<32, 256, 0, stream>>>(st31, out1);
    fft_h_inv_kernel<<<1024, 256, 0, stream>>>(Hf);
    mix_mfma_kernel<1><<<2048, 256, 0, stream>>>(Hf, Apack, bc_re, bc_im, pl, out0, lnpart);
    ln_finish_kernel<<<64, 64, 0, stream>>>(lnpart, stats);
    ln_apply_kernel<<<8192, 256, 0, stream>>>(out0, x, ln_w, ln_b, stats);
}

// Round 7
// 129.929 us; speedup vs baseline: 3.4529x; 1.1589x over previous
//
#include <hip/hip_runtime.h>
#include <cstdint>
#include <cstddef>

#define DEVINL __device__ __forceinline__

static constexpr int Bdim = 2, Ldim = 32, Cdim = 128, Hdim = 32, Wdim = 32;
static constexpr int HW  = Hdim * Wdim;         // 1024
static constexpr int CHW = Cdim * HW;           // 131072
static constexpr size_t OUT0_ELEMS = (size_t)Bdim * Ldim * CHW;  // 8388608
static constexpr size_t OUT1_CPLX  = (size_t)Bdim * CHW;         // 262144 complex elems

typedef __attribute__((ext_vector_type(8))) short short8v;   // 8 bf16 (4 VGPR)
typedef __attribute__((ext_vector_type(4))) float f32x4;     // MFMA C/D

DEVINL int bitrev5(int v) {
    return ((v&1)<<4) | ((v&2)<<2) | (v&4) | ((v&8)>>2) | ((v&16)>>4);
}
DEVINL unsigned short f2bf(float v) {               // RNE f32 -> bf16 bits
    unsigned u = __float_as_uint(v);
    return (unsigned short)((u + 0x7FFFu + ((u >> 16) & 1u)) >> 16);
}
DEVINL void bfsplit(float v, short& hi, short& lo) {
    unsigned short hb = f2bf(v);
    hi = (short)hb;
    float hf = __uint_as_float(((unsigned)hb) << 16);
    lo = (short)f2bf(v - hf);
}

// ================= 32-point radix-2 DIT FFT, fully in registers =================
template<int INV>
DEVINL void fft32_reg(float2 v[32]) {
    constexpr float TC[16] = { 1.0f, 0.980785280f, 0.923879533f, 0.831469612f,
                               0.707106781f, 0.555570233f, 0.382683432f, 0.195090322f,
                               0.0f, -0.195090322f, -0.382683432f, -0.555570233f,
                              -0.707106781f, -0.831469612f, -0.923879533f, -0.980785280f };
    constexpr float TS[16] = { 0.0f, -0.195090322f, -0.382683432f, -0.555570233f,
                              -0.707106781f, -0.831469612f, -0.923879533f, -0.980785280f,
                              -1.0f, -0.980785280f, -0.923879533f, -0.831469612f,
                              -0.707106781f, -0.555570233f, -0.382683432f, -0.195090322f };
#pragma unroll
    for (int st = 0; st < 5; ++st) {
        const int half = 1 << st;
#pragma unroll
        for (int bf = 0; bf < 16; ++bf) {
            const int g = bf >> st;
            const int j = bf & (half - 1);
            const int i0 = (g << (st+1)) + j;
            const float wr = TC[j << (4-st)];
            const float wi = INV ? -TS[j << (4-st)] : TS[j << (4-st)];
            float2 a0 = v[i0], a1 = v[i0+half];
            float tr = wr*a1.x - wi*a1.y;
            float ti = wr*a1.y + wi*a1.x;
            v[i0]      = make_float2(a0.x+tr, a0.y+ti);
            v[i0+half] = make_float2(a0.x-tr, a0.y-ti);
        }
    }
}

// =========================================================================
// Packed bf16 B-operand plane layout (shorts):
//   P[(bl*32 + h)*8192 + kc*1024 + nt2*512 + ln*8 + j]
// kc 0..3: Re of channel c = kc*32 + (ln>>4)*8 + j ; kc 4..7: Im (c likewise)
// nt2 = w>>4, ln = ((c>>3)&3)*16 + (w&15), j = c&7.
// This is byte-identical to the LDS image the MFMA mix consumes.
// =========================================================================

// ---- forward FFT along H (real input) + pack to bf16 fragment plane ----
__global__ __launch_bounds__(256) void fft_pack_fwd_kernel(const float* __restrict__ x,
                                                           short* __restrict__ P) {
    __shared__ short T[32][2][2][16][8];   // [h][re/im][nt][wl][ci] = 32 KB
    const int blk = blockIdx.x;            // 64 bl * 16 cg
    const int bl = blk >> 4, cg = blk & 15;
    const int t = threadIdx.x;
    const int ci = t >> 5, w = t & 31;
    const int c = cg*8 + ci;
    const float* src = x + ((size_t)(bl*Cdim + c))*HW + w;
    float2 v[32];
#pragma unroll
    for (int i = 0; i < 32; ++i)
        v[i] = make_float2(src[(size_t)bitrev5(i)*Wdim], 0.f);
    fft32_reg<0>(v);
#pragma unroll
    for (int h = 0; h < 32; ++h) {
        T[h][0][w>>4][w&15][ci] = (short)f2bf(v[h].x);
        T[h][1][w>>4][w&15][ci] = (short)f2bf(v[h].y);
    }
    __syncthreads();
    const int kc0 = cg >> 2, lnb = (cg & 3) * 16;
#pragma unroll
    for (int p = 0; p < 8; ++p) {
        const int lin = p*256 + t;            // 0..2047, 16B each
        const int h = lin >> 6, rem = lin & 63;
        const int pl = rem >> 5, nt = (rem >> 4) & 1, wl = rem & 15;
        const float4 val = *reinterpret_cast<const float4*>(&T[h][pl][nt][wl][0]);
        const size_t dst = ((size_t)(bl*32 + h)*8 + kc0 + pl*4)*1024
                         + (size_t)nt*512 + (size_t)(lnb + wl)*8;
        *reinterpret_cast<float4*>(P + dst) = val;
    }
}

// ---- inverse FFT along H of f32 complex (post-scan) + pack to bf16 plane ----
__global__ __launch_bounds__(256) void ifft_pack_kernel(const float2* __restrict__ Hf,
                                                        short* __restrict__ P) {
    __shared__ short T[32][2][2][16][8];   // 32 KB
    const int blk = blockIdx.x;            // 64 bl * 16 cg
    const int bl = blk >> 4, cg = blk & 15;
    const int t = threadIdx.x;
    const int ci = t >> 5, w = t & 31;
    const int c = cg*8 + ci;
    const float2* src = Hf + ((size_t)(bl*Cdim + c))*HW + w;
    float2 v[32];
#pragma unroll
    for (int i = 0; i < 32; ++i) v[i] = src[(size_t)bitrev5(i)*Wdim];
    fft32_reg<1>(v);
    const float sc = 1.0f / 32.0f;
#pragma unroll
    for (int h = 0; h < 32; ++h) {
        T[h][0][w>>4][w&15][ci] = (short)f2bf(v[h].x * sc);
        T[h][1][w>>4][w&15][ci] = (short)f2bf(v[h].y * sc);
    }
    __syncthreads();
    const int kc0 = cg >> 2, lnb = (cg & 3) * 16;
#pragma unroll
    for (int p = 0; p < 8; ++p) {
        const int lin = p*256 + t;
        const int h = lin >> 6, rem = lin & 63;
        const int pl = rem >> 5, nt = (rem >> 4) & 1, wl = rem & 15;
        const float4 val = *reinterpret_cast<const float4*>(&T[h][pl][nt][wl][0]);
        const size_t dst = ((size_t)(bl*32 + h)*8 + kc0 + pl*4)*1024
                         + (size_t)nt*512 + (size_t)(lnb + wl)*8;
        *reinterpret_cast<float4*>(P + dst) = val;
    }
}

// ---- forward FFT along W for out1 (l=31 state) ----
template<int CPLX>
__global__ __launch_bounds__(256) void fft_w_out1_kernel(const float2* __restrict__ st31,
                                                         float* __restrict__ out1) {
    const int row = blockIdx.x*256 + threadIdx.x;   // 0..8191 = (b,c,h)
    const float2* src = st31 + (size_t)row*32;
    float2 v[32];
#pragma unroll
    for (int i = 0; i < 32; ++i) v[i] = src[bitrev5(i)];
    fft32_reg<0>(v);
    if (CPLX) {
        float2* dst = reinterpret_cast<float2*>(out1) + (size_t)row*32;
#pragma unroll
        for (int i = 0; i < 32; ++i) dst[i] = v[i];
    } else {
        float* dst = out1 + (size_t)row*32;
#pragma unroll
        for (int i = 0; i < 32; ++i) dst[i] = v[i].x;
    }
}

// ======================= A-pack (unchanged, verified) ==========
__global__ __launch_bounds__(256) void pack_w_kernel(
    const float* __restrict__ Wb_re, const float* __restrict__ Wb_im,
    const float* __restrict__ Wc_re, const float* __restrict__ Wc_im,
    short* __restrict__ Apack)
{
    const int gid = blockIdx.x*256 + threadIdx.x;    // 0..12287
    const int a    = gid >> 12;
    const int rem  = gid & 4095;
    const int f    = rem >> 6;
    const int lane = rem & 63;
    const int m  = f >> 3, kc = f & 7;
    const int row = m*16 + (lane & 15);
    const int kbase = kc*32 + ((lane >> 4) << 3);
    short8v hi8, lo8;
#pragma unroll
    for (int j = 0; j < 8; ++j) {
        const int k = kbase + j;
        const int half = k >> 7;
        const int c = k & 127;
        float v;
        if (a == 0)      v = half ? -Wb_im[row*Cdim + c] : Wb_re[row*Cdim + c];
        else if (a == 1) v = half ?  Wb_re[row*Cdim + c] : Wb_im[row*Cdim + c];
        else             v = half ? -Wc_im[row*Cdim + c] : Wc_re[row*Cdim + c];
        short h, l; bfsplit(v, h, l);
        hi8[j] = h; lo8[j] = l;
    }
    const size_t off = (size_t)(f*64 + lane)*8;
    *reinterpret_cast<short8v*>(Apack + (size_t)(2*a)  *32768 + off) = hi8;
    *reinterpret_cast<short8v*>(Apack + (size_t)(2*a+1)*32768 + off) = lo8;
}

// ======================= MFMA channel mix v2: packed-bf16 B input ========
// Block: one (b,l) x 64 hw cols (tile tt covers h = 2tt, 2tt+1, all w).
// B hi-only; A split hi/lo.  MODE 0: complex out*(gamma), bias bb at w==0 only,
// writes f32 Hf.  MODE 1: real out + bc, writes out0 + LN partials.
template<int MODE>
__global__ __launch_bounds__(256) void mix_mfma2_kernel(
    const short* __restrict__ Pin,
    float2* __restrict__ Hf,
    const short* __restrict__ Apack,
    const float* __restrict__ bre, const float* __restrict__ bim,
    const float* __restrict__ pl,
    float* __restrict__ outr,
    float2* __restrict__ lnpart)
{
    __shared__ short Bs[8][4][64][8];    // 32 KB
    const int bx = blockIdx.x;           // 64 bl * 16 tt
    const int bl = bx >> 4, tt = bx & 15;
    const int t = threadIdx.x;
    const int wv = t >> 6, lane = t & 63;

    // ---- stage: pure coalesced copy of the packed fragments ----
    const short* src = Pin + (size_t)(bl*32 + tt*2)*8192;
#pragma unroll
    for (int q = 0; q < 8; ++q) {
        const int u = q*256 + t;                 // 0..2047 16B units
        const int kc = u >> 8, nt4 = (u >> 6) & 3, ln = u & 63;
        const short* s = src + (size_t)(nt4 >> 1)*8192 + kc*1024 + (nt4 & 1)*512 + ln*8;
        *reinterpret_cast<float4*>(&Bs[kc][nt4][ln][0]) =
            *reinterpret_cast<const float4*>(s);
    }
    __syncthreads();

    f32x4 accRe[2][4];
    f32x4 accIm[2][4];
#pragma unroll
    for (int mi = 0; mi < 2; ++mi)
#pragma unroll
        for (int nt = 0; nt < 4; ++nt) {
            accRe[mi][nt] = (f32x4)(0.0f);
            accIm[mi][nt] = (f32x4)(0.0f);
        }

    const short* Are_hi = Apack + (MODE == 0 ? 0 : 4)*32768;
    const short* Are_lo = Are_hi + 32768;
    const short* Aim_hi = Apack + 2*32768;   // MODE 0 only
    const short* Aim_lo = Aim_hi + 32768;

#pragma unroll 2
    for (int kc = 0; kc < 8; ++kc) {
        short8v bh[4];
#pragma unroll
        for (int nt = 0; nt < 4; ++nt)
            bh[nt] = *reinterpret_cast<const short8v*>(&Bs[kc][nt][lane][0]);
#pragma unroll
        for (int mi = 0; mi < 2; ++mi) {
            const int m = wv*2 + mi;
            const size_t off = (size_t)((m*8 + kc)*64 + lane)*8;
            const short8v arh = *reinterpret_cast<const short8v*>(Are_hi + off);
            const short8v arl = *reinterpret_cast<const short8v*>(Are_lo + off);
#pragma unroll
            for (int nt = 0; nt < 4; ++nt) {
                accRe[mi][nt] = __builtin_amdgcn_mfma_f32_16x16x32_bf16(arh, bh[nt], accRe[mi][nt], 0, 0, 0);
                accRe[mi][nt] = __builtin_amdgcn_mfma_f32_16x16x32_bf16(arl, bh[nt], accRe[mi][nt], 0, 0, 0);
            }
            if (MODE == 0) {
                const short8v aih = *reinterpret_cast<const short8v*>(Aim_hi + off);
                const short8v ail = *reinterpret_cast<const short8v*>(Aim_lo + off);
#pragma unroll
                for (int nt = 0; nt < 4; ++nt) {
                    accIm[mi][nt] = __builtin_amdgcn_mfma_f32_16x16x32_bf16(aih, bh[nt], accIm[mi][nt], 0, 0, 0);
                    accIm[mi][nt] = __builtin_amdgcn_mfma_f32_16x16x32_bf16(ail, bh[nt], accIm[mi][nt], 0, 0, 0);
                }
            }
        }
    }

    // ---- epilogue.  D layout: col = lane&15, row = (lane>>4)*4 + r ----
    const int col   = lane & 15;
    const int rbase = (lane >> 4) * 4;
    float lns = 0.f, lnq = 0.f;
#pragma unroll
    for (int mi = 0; mi < 2; ++mi) {
#pragma unroll
        for (int r = 0; r < 4; ++r) {
            const int o = wv*32 + mi*16 + rbase + r;
            if (MODE == 0) {
                const float br = bre[o], bi = bim[o];
                const float g0 = expf(pl[(2*Cdim + o)*Hdim + 2*tt]);
                const float g1 = expf(pl[(2*Cdim + o)*Hdim + 2*tt + 1]);
#pragma unroll
                for (int nt = 0; nt < 4; ++nt) {
                    const int wcol = nt*16 + col;
                    const float g = (nt < 2) ? g0 : g1;
                    // bias bb corresponds to bb * delta_{w==0} in this domain
                    const float bsel = ((wcol & 31) == 0) ? 1.0f : 0.0f;
                    float2 rv;
                    rv.x = (accRe[mi][nt][r] + br*bsel) * g;
                    rv.y = (accIm[mi][nt][r] + bi*bsel) * g;
                    Hf[(size_t)bl*CHW + (size_t)o*HW + tt*64 + wcol] = rv;
                }
            } else {
                const float br = bre[o];
#pragma unroll
                for (int nt = 0; nt < 4; ++nt) {
                    const int wcol = nt*16 + col;
                    const float v = accRe[mi][nt][r] + br;
                    outr[(size_t)bl*CHW + (size_t)o*HW + tt*64 + wcol] = v;
                    lns += v; lnq += v*v;
                }
            }
        }
    }
    if (MODE == 1) {
#pragma unroll
        for (int off = 32; off > 0; off >>= 1) {
            lns += __shfl_down(lns, off);
            lnq += __shfl_down(lnq, off);
        }
        __shared__ float2 red[4];
        if (lane == 0) red[wv] = make_float2(lns, lnq);
        __syncthreads();
        if (t == 0) {
            float2 a = red[0], b2 = red[1], c2 = red[2], d = red[3];
            lnpart[bx] = make_float2(a.x + b2.x + c2.x + d.x, a.y + b2.y + c2.y + d.y);
        }
    }
}

// ======================= scan over L (unchanged, verified) =======================
__global__ __launch_bounds__(256) void scan_kernel(
    float2* __restrict__ Hf, const float* __restrict__ pl, float2* __restrict__ st31)
{
    const int idx = blockIdx.x*256 + threadIdx.x;   // 0..262143 = B*C*H*W
    const int b   = idx >> 17;
    const int chw = idx & (CHW - 1);
    const int c   = chw >> 10;
    const int h   = (chw >> 5) & 31;
    const float nu = expf(pl[c*Hdim + h]);
    const float th = expf(pl[(Cdim + c)*Hdim + h]);
    const float rr = expf(-nu);
    const float lr = rr * cosf(th);
    const float li = rr * sinf(th);
    float2 y = make_float2(0.f, 0.f);
    const size_t basei = (size_t)b * Ldim * CHW + chw;
#pragma unroll 4
    for (int l = 0; l < Ldim; ++l) {
        float2 hv = Hf[basei + (size_t)l*CHW];
        float yr = fmaf(lr, y.x, fmaf(-li, y.y, hv.x));
        float yi = fmaf(lr, y.y, fmaf( li, y.x, hv.y));
        y = make_float2(yr, yi);
        Hf[basei + (size_t)l*CHW] = y;
    }
    st31[(size_t)b*CHW + chw] = y;
}

// ======================= LayerNorm finish + apply =======================
template<int NP>
__global__ __launch_bounds__(64) void ln_finish_kernel(const float2* __restrict__ lnpart,
                                                       float2* __restrict__ stats) {
    const int bl = blockIdx.x;
    const int t = threadIdx.x;
    float s = 0.f, sq = 0.f;
    if (t < NP) { float2 v = lnpart[bl*NP + t]; s = v.x; sq = v.y; }
#pragma unroll
    for (int off = NP/2; off > 0; off >>= 1) {
        s  += __shfl_down(s, off);
        sq += __shfl_down(sq, off);
    }
    if (t == 0) {
        const float invN = 1.0f / (float)CHW;
        float mean = s * invN;
        float var  = sq * invN - mean*mean;
        stats[bl] = make_float2(mean, rsqrtf(var + 1e-5f));
    }
}

__global__ __launch_bounds__(256) void ln_apply_kernel(
    float* __restrict__ out0, const float* __restrict__ x,
    const float* __restrict__ lnw, const float* __restrict__ lnb,
    const float2* __restrict__ stats)
{
    const int idx4 = blockIdx.x*256 + threadIdx.x;
    const int i = idx4 * 4;
    const int bl = i >> 17;
    const int chw4 = (i & (CHW - 1)) >> 2;
    const float2 st = stats[bl];
    float4 h  = reinterpret_cast<float4*>(out0)[idx4];
    float4 xv = reinterpret_cast<const float4*>(x)[idx4];
    float4 w  = reinterpret_cast<const float4*>(lnw)[chw4];
    float4 bb = reinterpret_cast<const float4*>(lnb)[chw4];
    const float m = st.x, rs = st.y;
    float4 r;
    r.x = fmaf((h.x - m)*rs, w.x, bb.x) + xv.x;
    r.y = fmaf((h.y - m)*rs, w.y, bb.y) + xv.y;
    r.z = fmaf((h.z - m)*rs, w.z, bb.z) + xv.z;
    r.w = fmaf((h.w - m)*rs, w.w, bb.w) + xv.w;
    reinterpret_cast<float4*>(out0)[idx4] = r;
}

// ======================= fallback (round-6 verified) kernels =======================
__global__ __launch_bounds__(256) void fft_h_fwd_kernel(const float* __restrict__ x,
                                                        float2* __restrict__ Hf) {
    const int gid = blockIdx.x*256 + threadIdx.x;
    const int w = gid & 31;
    const size_t slice = (size_t)(gid >> 5);
    const float* src = x + slice*HW + w;
    float2 v[32];
#pragma unroll
    for (int i = 0; i < 32; ++i)
        v[i] = make_float2(src[(size_t)bitrev5(i)*Wdim], 0.f);
    fft32_reg<0>(v);
    float2* dst = Hf + slice*HW + w;
#pragma unroll
    for (int h = 0; h < 32; ++h) dst[(size_t)h*Wdim] = v[h];
}

__global__ __launch_bounds__(256) void fft_h_inv_kernel(float2* __restrict__ Hf) {
    const int gid = blockIdx.x*256 + threadIdx.x;
    const int w = gid & 31;
    const size_t slice = (size_t)(gid >> 5);
    float2* p = Hf + slice*HW + w;
    float2 v[32];
#pragma unroll
    for (int i = 0; i < 32; ++i) v[i] = p[(size_t)bitrev5(i)*Wdim];
    fft32_reg<1>(v);
    const float sc = 1.0f / 32.0f;
#pragma unroll
    for (int h = 0; h < 32; ++h)
        p[(size_t)h*Wdim] = make_float2(v[h].x*sc, v[h].y*sc);
}

template<int MODE>
__global__ __launch_bounds__(256) void mix_mfma_kernel(
    float2* __restrict__ Hf,
    const short* __restrict__ Apack,
    const float* __restrict__ bre, const float* __restrict__ bim,
    const float* __restrict__ pl,
    float* __restrict__ outr,
    float2* __restrict__ lnpart)
{
    __shared__ short Bhl[2][8][2][64][8];   // 32 KB
    const int bx  = blockIdx.x;
    const int bl  = bx >> 5;
    const int hw0 = (bx & 31) << 5;
    const int t   = threadIdx.x;
    const int wv  = t >> 6;
    const int lane = t & 63;
    float2* __restrict__ base = Hf + (size_t)bl * CHW;
#pragma unroll
    for (int i = 0; i < 2; ++i) {
        const int idx = i*256 + t;
        const int kc4 = (idx >> 7) & 3;
        const int nt  = (idx >> 6) & 1;
        const int ln  = idx & 63;
        const int c0  = kc4*32 + ((ln >> 4) << 3);
        const int n   = nt*16 + (ln & 15);
        const float2* src = base + (size_t)c0*HW + hw0 + n;
        short8v hre, lre, him, lim;
#pragma unroll
        for (int j = 0; j < 8; ++j) {
            float2 hv = src[(size_t)j*HW];
            short h, l;
            bfsplit(hv.x, h, l); hre[j] = h; lre[j] = l;
            bfsplit(hv.y, h, l); him[j] = h; lim[j] = l;
        }
        *reinterpret_cast<short8v*>(&Bhl[0][kc4][nt][ln][0])   = hre;
        *reinterpret_cast<short8v*>(&Bhl[0][kc4+4][nt][ln][0]) = him;
        *reinterpret_cast<short8v*>(&Bhl[1][kc4][nt][ln][0])   = lre;
        *reinterpret_cast<short8v*>(&Bhl[1][kc4+4][nt][ln][0]) = lim;
    }
    __syncthreads();
    f32x4 accRe[2][2];
    f32x4 accIm[2][2];
#pragma unroll
    for (int mi = 0; mi < 2; ++mi)
#pragma unroll
        for (int nt = 0; nt < 2; ++nt) {
            accRe[mi][nt] = (f32x4)(0.0f);
            accIm[mi][nt] = (f32x4)(0.0f);
        }
    const short* Are_hi = Apack + (MODE == 0 ? 0 : 4)*32768;
    const short* Are_lo = Are_hi + 32768;
    const short* Aim_hi = Apack + 2*32768;
    const short* Aim_lo = Aim_hi + 32768;
#pragma unroll 2
    for (int kc = 0; kc < 8; ++kc) {
        short8v bh[2], blo[2];
#pragma unroll
        for (int nt = 0; nt < 2; ++nt) {
            bh[nt]  = *reinterpret_cast<const short8v*>(&Bhl[0][kc][nt][lane][0]);
            blo[nt] = *reinterpret_cast<const short8v*>(&Bhl[1][kc][nt][lane][0]);
        }
#pragma unroll
        for (int mi = 0; mi < 2; ++mi) {
            const int m = wv*2 + mi;
            const size_t off = (size_t)((m*8 + kc)*64 + lane)*8;
            const short8v arh = *reinterpret_cast<const short8v*>(Are_hi + off);
            const short8v arl = *reinterpret_cast<const short8v*>(Are_lo + off);
#pragma unroll
            for (int nt = 0; nt < 2; ++nt) {
                accRe[mi][nt] = __builtin_amdgcn_mfma_f32_16x16x32_bf16(arh, bh[nt],  accRe[mi][nt], 0, 0, 0);
                accRe[mi][nt] = __builtin_amdgcn_mfma_f32_16x16x32_bf16(arh, blo[nt], accRe[mi][nt], 0, 0, 0);
                accRe[mi][nt] = __builtin_amdgcn_mfma_f32_16x16x32_bf16(arl, bh[nt],  accRe[mi][nt], 0, 0, 0);
            }
            if (MODE == 0) {
                const short8v aih = *reinterpret_cast<const short8v*>(Aim_hi + off);
                const short8v ail = *reinterpret_cast<const short8v*>(Aim_lo + off);
#pragma unroll
                for (int nt = 0; nt < 2; ++nt) {
                    accIm[mi][nt] = __builtin_amdgcn_mfma_f32_16x16x32_bf16(aih, bh[nt],  accIm[mi][nt], 0, 0, 0);
                    accIm[mi][nt] = __builtin_amdgcn_mfma_f32_16x16x32_bf16(aih, blo[nt], accIm[mi][nt], 0, 0, 0);
                    accIm[mi][nt] = __builtin_amdgcn_mfma_f32_16x16x32_bf16(ail, bh[nt],  accIm[mi][nt], 0, 0, 0);
                }
            }
        }
    }
    const int col   = lane & 15;
    const int rbase = (lane >> 4) * 4;
    const int h0    = hw0 >> 5;
    float lns = 0.f, lnq = 0.f;
#pragma unroll
    for (int mi = 0; mi < 2; ++mi) {
#pragma unroll
        for (int r = 0; r < 4; ++r) {
            const int o = wv*32 + mi*16 + rbase + r;
            if (MODE == 0) {
                const float br = bre[o], bi = bim[o];
                const float g = expf(pl[(2*Cdim + o)*Hdim + h0]);
#pragma unroll
                for (int nt = 0; nt < 2; ++nt) {
                    const int wcol = nt*16 + col;
                    const float bsel = (wcol == 0) ? 1.0f : 0.0f;
                    const int hw = hw0 + wcol;
                    float2 rv;
                    rv.x = (accRe[mi][nt][r] + br*bsel) * g;
                    rv.y = (accIm[mi][nt][r] + bi*bsel) * g;
                    base[(size_t)o*HW + hw] = rv;
                }
            } else {
                const float br = bre[o];
#pragma unroll
                for (int nt = 0; nt < 2; ++nt) {
                    const int hw = hw0 + nt*16 + col;
                    const float v = accRe[mi][nt][r] + br;
                    outr[(size_t)bl*CHW + (size_t)o*HW + hw] = v;
                    lns += v; lnq += v*v;
                }
            }
        }
    }
    if (MODE == 1) {
#pragma unroll
        for (int off = 32; off > 0; off >>= 1) {
            lns += __shfl_down(lns, off);
            lnq += __shfl_down(lnq, off);
        }
        __shared__ float2 red[4];
        if (lane == 0) red[wv] = make_float2(lns, lnq);
        __syncthreads();
        if (t == 0) {
            float2 a = red[0], b2 = red[1], c2 = red[2], d = red[3];
            lnpart[bx] = make_float2(a.x + b2.x + c2.x + d.x, a.y + b2.y + c2.y + d.y);
        }
    }
}

// ======================= launch =======================
extern "C" void kernel_launch(void* const* d_in, const int* in_sizes, int n_in,
                              void* d_out, int out_size, void* d_ws, size_t ws_size,
                              hipStream_t stream)
{
    const float* x     = (const float*)d_in[0];
    const float* pl    = (const float*)d_in[1];
    const float* Wb_re = (const float*)d_in[2];
    const float* Wb_im = (const float*)d_in[3];
    const float* bb_re = (const float*)d_in[4];
    const float* bb_im = (const float*)d_in[5];
    const float* Wc_re = (const float*)d_in[6];
    const float* Wc_im = (const float*)d_in[7];
    const float* bc_re = (const float*)d_in[8];
    const float* bc_im = (const float*)d_in[9];
    const float* ln_w  = (const float*)d_in[10];
    const float* ln_b  = (const float*)d_in[11];

    float* out0 = (float*)d_out;
    float* out1 = out0 + OUT0_ELEMS;

    char* ws = (char*)d_ws;
    float2* Hf      = (float2*)ws;                                      // 67,108,864 B
    float2* lnpart  = (float2*)(ws + 67108864);                          // 16 KB
    float2* stats   = (float2*)(ws + 67108864 + 16384);                  // 512 B
    short*  Apack   = (short*) (ws + 67108864 + 16896);                  // 384 KB
    float2* st31    = (float2*)(ws + 67108864 + 16896 + 393216);         // 2 MB
    short*  Ppack   = (short*) (ws + 67108864 + 16896 + 393216 + 2097152); // 33,554,432 B
    const size_t NEED = 67108864ull + 16896 + 393216 + 2097152 + 33554432;

    const bool interleaved = ((size_t)out_size >= OUT0_ELEMS + 2*OUT1_CPLX);

    pack_w_kernel<<<48, 256, 0, stream>>>(Wb_re, Wb_im, Wc_re, Wc_im, Apack);

    if (ws_size >= NEED) {
        // ---- fast path: packed-bf16 B operands ----
        fft_pack_fwd_kernel<<<1024, 256, 0, stream>>>(x, Ppack);
        mix_mfma2_kernel<0><<<1024, 256, 0, stream>>>(Ppack, Hf, Apack, bb_re, bb_im, pl, nullptr, nullptr);
        scan_kernel<<<1024, 256, 0, stream>>>(Hf, pl, st31);
        if (interleaved)
            fft_w_out1_kernel<1><<<32, 256, 0, stream>>>(st31, out1);
        else
            fft_w_out1_kernel<0><<<32, 256, 0, stream>>>(st31, out1);
        ifft_pack_kernel<<<1024, 256, 0, stream>>>(Hf, Ppack);
        mix_mfma2_kernel<1><<<1024, 256, 0, stream>>>(Ppack, nullptr, Apack, bc_re, bc_im, pl, out0, lnpart);
        ln_finish_kernel<16><<<64, 64, 0, stream>>>(lnpart, stats);
    } else {
        // ---- fallback: round-6 verified path ----
        fft_h_fwd_kernel<<<1024, 256, 0, stream>>>(x, Hf);
        mix_mfma_kernel<0><<<2048, 256, 0, stream>>>(Hf, Apack, bb_re, bb_im, pl, nullptr, nullptr);
        scan_kernel<<<1024, 256, 0, stream>>>(Hf, pl, st31);
        if (interleaved)
            fft_w_out1_kernel<1><<<32, 256, 0, stream>>>(st31, out1);
        else
            fft_w_out1_kernel<0><<<32, 256, 0, stream>>>(st31, out1);
        fft_h_inv_kernel<<<1024, 256, 0, stream>>>(Hf);
        mix_mfma_kernel<1><<<2048, 256, 0, stream>>>(Hf, Apack, bc_re, bc_im, pl, out0, lnpart);
        ln_finish_kernel<32><<<64, 64, 0, stream>>>(lnpart, stats);
    }
    ln_apply_kernel<<<8192, 256, 0, stream>>>(out0, x, ln_w, ln_b, stats);
}

// Round 8
// 108.655 us; speedup vs baseline: 4.1290x; 1.1958x over previous
//
#include <hip/hip_runtime.h>
#include <cstdint>
#include <cstddef>

#define DEVINL __device__ __forceinline__

static constexpr int Bdim = 2, Ldim = 32, Cdim = 128, Hdim = 32, Wdim = 32;
static constexpr int HW  = Hdim * Wdim;         // 1024
static constexpr int CHW = Cdim * HW;           // 131072
static constexpr size_t OUT0_ELEMS = (size_t)Bdim * Ldim * CHW;  // 8388608
static constexpr size_t OUT1_CPLX  = (size_t)Bdim * CHW;         // 262144 complex elems

typedef __attribute__((ext_vector_type(8))) short short8v;   // 8 bf16 (4 VGPR)
typedef __attribute__((ext_vector_type(4))) float f32x4;     // MFMA C/D

DEVINL int bitrev5(int v) {
    return ((v&1)<<4) | ((v&2)<<2) | (v&4) | ((v&8)>>2) | ((v&16)>>4);
}
DEVINL unsigned short f2bf(float v) {               // RNE f32 -> bf16 bits
    unsigned u = __float_as_uint(v);
    return (unsigned short)((u + 0x7FFFu + ((u >> 16) & 1u)) >> 16);
}
DEVINL float bf2f(unsigned short b) { return __uint_as_float(((unsigned)b) << 16); }
DEVINL void bfsplit(float v, short& hi, short& lo) {
    unsigned short hb = f2bf(v);
    hi = (short)hb;
    float hf = bf2f(hb);
    lo = (short)f2bf(v - hf);
}
DEVINL unsigned pack2bf(float2 v) {
    return (unsigned)f2bf(v.x) | ((unsigned)f2bf(v.y) << 16);
}
DEVINL float2 unpack2bf(unsigned u) {
    return make_float2(__uint_as_float(u << 16), __uint_as_float(u & 0xFFFF0000u));
}

// ================= 32-point radix-2 DIT FFT, fully in registers =================
template<int INV>
DEVINL void fft32_reg(float2 v[32]) {
    constexpr float TC[16] = { 1.0f, 0.980785280f, 0.923879533f, 0.831469612f,
                               0.707106781f, 0.555570233f, 0.382683432f, 0.195090322f,
                               0.0f, -0.195090322f, -0.382683432f, -0.555570233f,
                              -0.707106781f, -0.831469612f, -0.923879533f, -0.980785280f };
    constexpr float TS[16] = { 0.0f, -0.195090322f, -0.382683432f, -0.555570233f,
                              -0.707106781f, -0.831469612f, -0.923879533f, -0.980785280f,
                              -1.0f, -0.980785280f, -0.923879533f, -0.831469612f,
                              -0.707106781f, -0.555570233f, -0.382683432f, -0.195090322f };
#pragma unroll
    for (int st = 0; st < 5; ++st) {
        const int half = 1 << st;
#pragma unroll
        for (int bf = 0; bf < 16; ++bf) {
            const int g = bf >> st;
            const int j = bf & (half - 1);
            const int i0 = (g << (st+1)) + j;
            const float wr = TC[j << (4-st)];
            const float wi = INV ? -TS[j << (4-st)] : TS[j << (4-st)];
            float2 a0 = v[i0], a1 = v[i0+half];
            float tr = wr*a1.x - wi*a1.y;
            float ti = wr*a1.y + wi*a1.x;
            v[i0]      = make_float2(a0.x+tr, a0.y+ti);
            v[i0+half] = make_float2(a0.x-tr, a0.y-ti);
        }
    }
}

// =========================================================================
// Packed bf16 B-operand plane layout (shorts):
//   P[(bl*32 + h)*8192 + kc*1024 + nt2*512 + ln*8 + j]
// kc 0..3: Re of channel c = kc*32 + (ln>>4)*8 + j ; kc 4..7: Im.
// nt2 = w>>4, ln = ((c>>3)&3)*16 + (w&15), j = c&7.
// =========================================================================

// ---- forward FFT along H (real input) + pack to bf16 fragment plane ----
__global__ __launch_bounds__(256) void fft_pack_fwd_kernel(const float* __restrict__ x,
                                                           short* __restrict__ P) {
    __shared__ short T[32][2][2][16][8];   // [h][re/im][nt][wl][ci] = 32 KB
    const int blk = blockIdx.x;            // 64 bl * 16 cg
    const int bl = blk >> 4, cg = blk & 15;
    const int t = threadIdx.x;
    const int ci = t >> 5, w = t & 31;
    const int c = cg*8 + ci;
    const float* src = x + ((size_t)(bl*Cdim + c))*HW + w;
    float2 v[32];
#pragma unroll
    for (int i = 0; i < 32; ++i)
        v[i] = make_float2(src[(size_t)bitrev5(i)*Wdim], 0.f);
    fft32_reg<0>(v);
#pragma unroll
    for (int h = 0; h < 32; ++h) {
        T[h][0][w>>4][w&15][ci] = (short)f2bf(v[h].x);
        T[h][1][w>>4][w&15][ci] = (short)f2bf(v[h].y);
    }
    __syncthreads();
    const int kc0 = cg >> 2, lnb = (cg & 3) * 16;
#pragma unroll
    for (int p = 0; p < 8; ++p) {
        const int lin = p*256 + t;            // 0..2047, 16B each
        const int h = lin >> 6, rem = lin & 63;
        const int pl = rem >> 5, nt = (rem >> 4) & 1, wl = rem & 15;
        const float4 val = *reinterpret_cast<const float4*>(&T[h][pl][nt][wl][0]);
        const size_t dst = ((size_t)(bl*32 + h)*8 + kc0 + pl*4)*1024
                         + (size_t)nt*512 + (size_t)(lnb + wl)*8;
        *reinterpret_cast<float4*>(P + dst) = val;
    }
}

// ---- inverse FFT along H of bf16x2 complex (post-scan) + pack to bf16 plane ----
__global__ __launch_bounds__(256) void ifft_pack_kernel(const unsigned* __restrict__ Hf2,
                                                        short* __restrict__ P) {
    __shared__ short T[32][2][2][16][8];   // 32 KB
    const int blk = blockIdx.x;            // 64 bl * 16 cg
    const int bl = blk >> 4, cg = blk & 15;
    const int t = threadIdx.x;
    const int ci = t >> 5, w = t & 31;
    const int c = cg*8 + ci;
    const unsigned* src = Hf2 + ((size_t)(bl*Cdim + c))*HW + w;
    float2 v[32];
#pragma unroll
    for (int i = 0; i < 32; ++i) v[i] = unpack2bf(src[(size_t)bitrev5(i)*Wdim]);
    fft32_reg<1>(v);
    const float sc = 1.0f / 32.0f;
#pragma unroll
    for (int h = 0; h < 32; ++h) {
        T[h][0][w>>4][w&15][ci] = (short)f2bf(v[h].x * sc);
        T[h][1][w>>4][w&15][ci] = (short)f2bf(v[h].y * sc);
    }
    __syncthreads();
    const int kc0 = cg >> 2, lnb = (cg & 3) * 16;
#pragma unroll
    for (int p = 0; p < 8; ++p) {
        const int lin = p*256 + t;
        const int h = lin >> 6, rem = lin & 63;
        const int pl = rem >> 5, nt = (rem >> 4) & 1, wl = rem & 15;
        const float4 val = *reinterpret_cast<const float4*>(&T[h][pl][nt][wl][0]);
        const size_t dst = ((size_t)(bl*32 + h)*8 + kc0 + pl*4)*1024
                         + (size_t)nt*512 + (size_t)(lnb + wl)*8;
        *reinterpret_cast<float4*>(P + dst) = val;
    }
}

// ---- forward FFT along W for out1 (l=31 state, f32) ----
template<int CPLX>
__global__ __launch_bounds__(256) void fft_w_out1_kernel(const float2* __restrict__ st31,
                                                         float* __restrict__ out1) {
    const int row = blockIdx.x*256 + threadIdx.x;   // 0..8191 = (b,c,h)
    const float2* src = st31 + (size_t)row*32;
    float2 v[32];
#pragma unroll
    for (int i = 0; i < 32; ++i) v[i] = src[bitrev5(i)];
    fft32_reg<0>(v);
    if (CPLX) {
        float2* dst = reinterpret_cast<float2*>(out1) + (size_t)row*32;
#pragma unroll
        for (int i = 0; i < 32; ++i) dst[i] = v[i];
    } else {
        float* dst = out1 + (size_t)row*32;
#pragma unroll
        for (int i = 0; i < 32; ++i) dst[i] = v[i].x;
    }
}

// ======================= A-pack (unchanged, verified) ==========
__global__ __launch_bounds__(256) void pack_w_kernel(
    const float* __restrict__ Wb_re, const float* __restrict__ Wb_im,
    const float* __restrict__ Wc_re, const float* __restrict__ Wc_im,
    short* __restrict__ Apack)
{
    const int gid = blockIdx.x*256 + threadIdx.x;    // 0..12287
    const int a    = gid >> 12;
    const int rem  = gid & 4095;
    const int f    = rem >> 6;
    const int lane = rem & 63;
    const int m  = f >> 3, kc = f & 7;
    const int row = m*16 + (lane & 15);
    const int kbase = kc*32 + ((lane >> 4) << 3);
    short8v hi8, lo8;
#pragma unroll
    for (int j = 0; j < 8; ++j) {
        const int k = kbase + j;
        const int half = k >> 7;
        const int c = k & 127;
        float v;
        if (a == 0)      v = half ? -Wb_im[row*Cdim + c] : Wb_re[row*Cdim + c];
        else if (a == 1) v = half ?  Wb_re[row*Cdim + c] : Wb_im[row*Cdim + c];
        else             v = half ? -Wc_im[row*Cdim + c] : Wc_re[row*Cdim + c];
        short h, l; bfsplit(v, h, l);
        hi8[j] = h; lo8[j] = l;
    }
    const size_t off = (size_t)(f*64 + lane)*8;
    *reinterpret_cast<short8v*>(Apack + (size_t)(2*a)  *32768 + off) = hi8;
    *reinterpret_cast<short8v*>(Apack + (size_t)(2*a+1)*32768 + off) = lo8;
}

// ======================= MFMA channel mix: packed-bf16 B input ========
// Block: one (b,l) x 64 hw cols (tile tt covers h = 2tt, 2tt+1, all w).
// B hi-only; A split hi/lo.
// MODE 0: complex out*(gamma), bias bb at w==0 only -> bf16x2 Hf2.
// MODE 1: real out + bc -> bf16 out0pre + f32 LN partials.
template<int MODE>
__global__ __launch_bounds__(256) void mix_mfma2_kernel(
    const short* __restrict__ Pin,
    unsigned* __restrict__ Hf2,
    const short* __restrict__ Apack,
    const float* __restrict__ bre, const float* __restrict__ bim,
    const float* __restrict__ pl,
    unsigned short* __restrict__ outr,
    float2* __restrict__ lnpart)
{
    __shared__ short Bs[8][4][64][8];    // 32 KB
    const int bx = blockIdx.x;           // 64 bl * 16 tt
    const int bl = bx >> 4, tt = bx & 15;
    const int t = threadIdx.x;
    const int wv = t >> 6, lane = t & 63;

    // ---- stage: pure coalesced copy of the packed fragments ----
    const short* src = Pin + (size_t)(bl*32 + tt*2)*8192;
#pragma unroll
    for (int q = 0; q < 8; ++q) {
        const int u = q*256 + t;                 // 0..2047 16B units
        const int kc = u >> 8, nt4 = (u >> 6) & 3, ln = u & 63;
        const short* s = src + (size_t)(nt4 >> 1)*8192 + kc*1024 + (nt4 & 1)*512 + ln*8;
        *reinterpret_cast<float4*>(&Bs[kc][nt4][ln][0]) =
            *reinterpret_cast<const float4*>(s);
    }
    __syncthreads();

    f32x4 accRe[2][4];
    f32x4 accIm[2][4];
#pragma unroll
    for (int mi = 0; mi < 2; ++mi)
#pragma unroll
        for (int nt = 0; nt < 4; ++nt) {
            accRe[mi][nt] = (f32x4)(0.0f);
            accIm[mi][nt] = (f32x4)(0.0f);
        }

    const short* Are_hi = Apack + (MODE == 0 ? 0 : 4)*32768;
    const short* Are_lo = Are_hi + 32768;
    const short* Aim_hi = Apack + 2*32768;   // MODE 0 only
    const short* Aim_lo = Aim_hi + 32768;

#pragma unroll 2
    for (int kc = 0; kc < 8; ++kc) {
        short8v bh[4];
#pragma unroll
        for (int nt = 0; nt < 4; ++nt)
            bh[nt] = *reinterpret_cast<const short8v*>(&Bs[kc][nt][lane][0]);
#pragma unroll
        for (int mi = 0; mi < 2; ++mi) {
            const int m = wv*2 + mi;
            const size_t off = (size_t)((m*8 + kc)*64 + lane)*8;
            const short8v arh = *reinterpret_cast<const short8v*>(Are_hi + off);
            const short8v arl = *reinterpret_cast<const short8v*>(Are_lo + off);
#pragma unroll
            for (int nt = 0; nt < 4; ++nt) {
                accRe[mi][nt] = __builtin_amdgcn_mfma_f32_16x16x32_bf16(arh, bh[nt], accRe[mi][nt], 0, 0, 0);
                accRe[mi][nt] = __builtin_amdgcn_mfma_f32_16x16x32_bf16(arl, bh[nt], accRe[mi][nt], 0, 0, 0);
            }
            if (MODE == 0) {
                const short8v aih = *reinterpret_cast<const short8v*>(Aim_hi + off);
                const short8v ail = *reinterpret_cast<const short8v*>(Aim_lo + off);
#pragma unroll
                for (int nt = 0; nt < 4; ++nt) {
                    accIm[mi][nt] = __builtin_amdgcn_mfma_f32_16x16x32_bf16(aih, bh[nt], accIm[mi][nt], 0, 0, 0);
                    accIm[mi][nt] = __builtin_amdgcn_mfma_f32_16x16x32_bf16(ail, bh[nt], accIm[mi][nt], 0, 0, 0);
                }
            }
        }
    }

    // ---- epilogue.  D layout: col = lane&15, row = (lane>>4)*4 + r ----
    const int col   = lane & 15;
    const int rbase = (lane >> 4) * 4;
    float lns = 0.f, lnq = 0.f;
#pragma unroll
    for (int mi = 0; mi < 2; ++mi) {
#pragma unroll
        for (int r = 0; r < 4; ++r) {
            const int o = wv*32 + mi*16 + rbase + r;
            if (MODE == 0) {
                const float br = bre[o], bi = bim[o];
                const float g0 = expf(pl[(2*Cdim + o)*Hdim + 2*tt]);
                const float g1 = expf(pl[(2*Cdim + o)*Hdim + 2*tt + 1]);
#pragma unroll
                for (int nt = 0; nt < 4; ++nt) {
                    const int wcol = nt*16 + col;
                    const float g = (nt < 2) ? g0 : g1;
                    const float bsel = ((wcol & 31) == 0) ? 1.0f : 0.0f;
                    float2 rv;
                    rv.x = (accRe[mi][nt][r] + br*bsel) * g;
                    rv.y = (accIm[mi][nt][r] + bi*bsel) * g;
                    Hf2[(size_t)bl*CHW + (size_t)o*HW + tt*64 + wcol] = pack2bf(rv);
                }
            } else {
                const float br = bre[o];
#pragma unroll
                for (int nt = 0; nt < 4; ++nt) {
                    const int wcol = nt*16 + col;
                    const float v = accRe[mi][nt][r] + br;
                    outr[(size_t)bl*CHW + (size_t)o*HW + tt*64 + wcol] = f2bf(v);
                    lns += v; lnq += v*v;
                }
            }
        }
    }
    if (MODE == 1) {
#pragma unroll
        for (int off = 32; off > 0; off >>= 1) {
            lns += __shfl_down(lns, off);
            lnq += __shfl_down(lnq, off);
        }
        __shared__ float2 red[4];
        if (lane == 0) red[wv] = make_float2(lns, lnq);
        __syncthreads();
        if (t == 0) {
            float2 a = red[0], b2 = red[1], c2 = red[2], d = red[3];
            lnpart[bx] = make_float2(a.x + b2.x + c2.x + d.x, a.y + b2.y + c2.y + d.y);
        }
    }
}

// ======================= scan over L (bf16x2 in/out, f32 state) =======================
__global__ __launch_bounds__(256) void scan_kernel(
    unsigned* __restrict__ Hf2, const float* __restrict__ pl, float2* __restrict__ st31)
{
    const int idx = blockIdx.x*256 + threadIdx.x;   // 0..262143 = B*C*H*W
    const int b   = idx >> 17;
    const int chw = idx & (CHW - 1);
    const int c   = chw >> 10;
    const int h   = (chw >> 5) & 31;
    const float nu = expf(pl[c*Hdim + h]);
    const float th = expf(pl[(Cdim + c)*Hdim + h]);
    const float rr = expf(-nu);
    const float lr = rr * cosf(th);
    const float li = rr * sinf(th);
    float2 y = make_float2(0.f, 0.f);
    const size_t basei = (size_t)b * Ldim * CHW + chw;
#pragma unroll 4
    for (int l = 0; l < Ldim; ++l) {
        float2 hv = unpack2bf(Hf2[basei + (size_t)l*CHW]);
        float yr = fmaf(lr, y.x, fmaf(-li, y.y, hv.x));
        float yi = fmaf(lr, y.y, fmaf( li, y.x, hv.y));
        y = make_float2(yr, yi);
        Hf2[basei + (size_t)l*CHW] = pack2bf(y);
    }
    st31[(size_t)b*CHW + chw] = y;
}

// ======================= LayerNorm finish + apply =======================
__global__ __launch_bounds__(64) void ln_finish_kernel(const float2* __restrict__ lnpart,
                                                       float2* __restrict__ stats) {
    const int bl = blockIdx.x;
    const int t = threadIdx.x;
    float s = 0.f, sq = 0.f;
    if (t < 16) { float2 v = lnpart[bl*16 + t]; s = v.x; sq = v.y; }
#pragma unroll
    for (int off = 8; off > 0; off >>= 1) {
        s  += __shfl_down(s, off);
        sq += __shfl_down(sq, off);
    }
    if (t == 0) {
        const float invN = 1.0f / (float)CHW;
        float mean = s * invN;
        float var  = sq * invN - mean*mean;
        stats[bl] = make_float2(mean, rsqrtf(var + 1e-5f));
    }
}

__global__ __launch_bounds__(256) void ln_apply_kernel(
    float* __restrict__ out0, const unsigned short* __restrict__ hpre,
    const float* __restrict__ x,
    const float* __restrict__ lnw, const float* __restrict__ lnb,
    const float2* __restrict__ stats)
{
    const int idx4 = blockIdx.x*256 + threadIdx.x;   // 4 elems per thread
    const int i = idx4 * 4;
    const int bl = i >> 17;
    const int chw4 = (i & (CHW - 1)) >> 2;
    const float2 st = stats[bl];
    const uint2 hu = reinterpret_cast<const uint2*>(hpre)[idx4];
    float4 h;
    h.x = __uint_as_float(hu.x << 16);
    h.y = __uint_as_float(hu.x & 0xFFFF0000u);
    h.z = __uint_as_float(hu.y << 16);
    h.w = __uint_as_float(hu.y & 0xFFFF0000u);
    float4 xv = reinterpret_cast<const float4*>(x)[idx4];
    float4 w  = reinterpret_cast<const float4*>(lnw)[chw4];
    float4 bb = reinterpret_cast<const float4*>(lnb)[chw4];
    const float m = st.x, rs = st.y;
    float4 r;
    r.x = fmaf((h.x - m)*rs, w.x, bb.x) + xv.x;
    r.y = fmaf((h.y - m)*rs, w.y, bb.y) + xv.y;
    r.z = fmaf((h.z - m)*rs, w.z, bb.z) + xv.z;
    r.w = fmaf((h.w - m)*rs, w.w, bb.w) + xv.w;
    reinterpret_cast<float4*>(out0)[idx4] = r;
}

// ======================= launch =======================
extern "C" void kernel_launch(void* const* d_in, const int* in_sizes, int n_in,
                              void* d_out, int out_size, void* d_ws, size_t ws_size,
                              hipStream_t stream)
{
    const float* x     = (const float*)d_in[0];
    const float* pl    = (const float*)d_in[1];
    const float* Wb_re = (const float*)d_in[2];
    const float* Wb_im = (const float*)d_in[3];
    const float* bb_re = (const float*)d_in[4];
    const float* bb_im = (const float*)d_in[5];
    const float* Wc_re = (const float*)d_in[6];
    const float* Wc_im = (const float*)d_in[7];
    const float* bc_re = (const float*)d_in[8];
    const float* bc_im = (const float*)d_in[9];
    const float* ln_w  = (const float*)d_in[10];
    const float* ln_b  = (const float*)d_in[11];

    float* out0 = (float*)d_out;
    float* out1 = out0 + OUT0_ELEMS;

    // workspace layout (≈87 MB; round-7 run proved ws >= 103 MB)
    char* ws = (char*)d_ws;
    short*          P       = (short*)          ws;                       // 33,554,432 B
    unsigned*       Hf2     = (unsigned*)       (ws + 33554432);           // 33,554,432 B
    unsigned short* out0pre = (unsigned short*) (ws + 67108864);           // 16,777,216 B
    float2*         st31    = (float2*)         (ws + 83886080);           //  2,097,152 B
    short*          Apack   = (short*)          (ws + 85983232);           //    393,216 B
    float2*         lnpart  = (float2*)         (ws + 86376448);           //      8,192 B
    float2*         stats   = (float2*)         (ws + 86384640);           //        512 B

    const bool interleaved = ((size_t)out_size >= OUT0_ELEMS + 2*OUT1_CPLX);

    pack_w_kernel<<<48, 256, 0, stream>>>(Wb_re, Wb_im, Wc_re, Wc_im, Apack);
    fft_pack_fwd_kernel<<<1024, 256, 0, stream>>>(x, P);
    mix_mfma2_kernel<0><<<1024, 256, 0, stream>>>(P, Hf2, Apack, bb_re, bb_im, pl, nullptr, nullptr);
    scan_kernel<<<1024, 256, 0, stream>>>(Hf2, pl, st31);
    if (interleaved)
        fft_w_out1_kernel<1><<<32, 256, 0, stream>>>(st31, out1);
    else
        fft_w_out1_kernel<0><<<32, 256, 0, stream>>>(st31, out1);
    ifft_pack_kernel<<<1024, 256, 0, stream>>>(Hf2, P);
    mix_mfma2_kernel<1><<<1024, 256, 0, stream>>>(P, nullptr, Apack, bc_re, bc_im, pl, out0pre, lnpart);
    ln_finish_kernel<<<64, 64, 0, stream>>>(lnpart, stats);
    ln_apply_kernel<<<8192, 256, 0, stream>>>(out0, out0pre, x, ln_w, ln_b, stats);
}